// Round 7
// baseline (196.490 us; speedup 1.0000x reference)
//
#include <hip/hip_runtime.h>

#define NEGF -9e15f

typedef __attribute__((ext_vector_type(8))) unsigned short u16x8;
typedef __attribute__((ext_vector_type(8))) short          s16x8;
typedef __attribute__((ext_vector_type(4))) float          f32x4;

// ---------- bf16 helpers (RTN-even) ----------
__device__ __forceinline__ unsigned short f2bf(float x) {
  union { float f; unsigned int u; } c; c.f = x;
  unsigned int r = c.u + 0x7fffu + ((c.u >> 16) & 1u);
  return (unsigned short)(r >> 16);
}
__device__ __forceinline__ float bf2f(unsigned short v) {
  union { float f; unsigned int u; } c; c.u = ((unsigned int)v) << 16;
  return c.f;
}

// ---------- async global->LDS, 16B per lane (wave-uniform LDS base) ----------
__device__ __forceinline__ void gload16(const void* g, void* l) {
  __builtin_amdgcn_global_load_lds(
      (const __attribute__((address_space(1))) unsigned int*)g,
      (__attribute__((address_space(3))) unsigned int*)l, 16, 0, 0);
}

// ---------- fp32 -> bf16 elementwise (optional scale) ----------
__global__ __launch_bounds__(256) void cvt_bf16(
    const float* __restrict__ in, unsigned short* __restrict__ out, int n, float scale)
{
  const int i = (blockIdx.x * 256 + threadIdx.x) * 4;
  if (i < n) {
    const float4 v = *(const float4*)(in + i);
    ushort4 o;
    o.x = f2bf(v.x * scale); o.y = f2bf(v.y * scale);
    o.z = f2bf(v.z * scale); o.w = f2bf(v.w * scale);
    *(ushort4*)(out + i) = o;
  }
}

// ---------- fp32 -> bf16 transposed (out[c][r] = in[r][c]) ----------
__global__ __launch_bounds__(256) void tcvt_bf16(
    const float* __restrict__ in, unsigned short* __restrict__ out, int R, int C)
{
  __shared__ float tile[32][33];
  const int bc = blockIdx.x * 32, br = blockIdx.y * 32;
  const int tx = threadIdx.x & 31, ty8 = threadIdx.x >> 5;
  #pragma unroll
  for (int j = 0; j < 32; j += 8)
    tile[ty8 + j][tx] = in[(size_t)(br + ty8 + j) * C + bc + tx];
  __syncthreads();
  #pragma unroll
  for (int j = 0; j < 32; j += 8)
    out[(size_t)(bc + ty8 + j) * R + br + tx] = f2bf(tile[tx][ty8 + j]);
}

// bov[g] = sum_f Wo[g][f] * bv[f]
__global__ __launch_bounds__(256) void bov_kernel(
    const float* __restrict__ Wo, const float* __restrict__ bv,
    float* __restrict__ bov)
{
  const int g    = blockIdx.x * 4 + (threadIdx.x >> 6);
  const int lane = threadIdx.x & 63;
  float acc = 0.f;
  for (int f = lane; f < 1024; f += 64)
    acc = fmaf(Wo[(size_t)g * 1024 + f], bv[f], acc);
  #pragma unroll
  for (int off = 32; off > 0; off >>= 1) acc += __shfl_down(acc, off);
  if (lane == 0) bov[g] = acc;
}

// ball[0:1024) = 0.125*bq ; ball[1024:2048) = bk
__global__ __launch_bounds__(256) void bias_prep(
    const float* __restrict__ bq, const float* __restrict__ bk,
    float* __restrict__ ball)
{
  const int i = blockIdx.x * 256 + threadIdx.x;
  ball[i]        = 0.125f * bq[i];
  ball[1024 + i] = bk[i];
}

// mb[i] = adj[i] > 0 ? lab[i] : NEG
__global__ __launch_bounds__(256) void mb_prep(
    const int* __restrict__ adj, const float* __restrict__ lab,
    float* __restrict__ mb)
{
  const int i = (blockIdx.x * 256 + threadIdx.x) * 4;
  const int4   a = *(const int4*)(adj + i);
  const float4 l = *(const float4*)(lab + i);
  float4 o;
  o.x = a.x > 0 ? l.x : NEGF;
  o.y = a.y > 0 ? l.y : NEGF;
  o.z = a.z > 0 ? l.z : NEGF;
  o.w = a.w > 0 ? l.w : NEGF;
  *(float4*)(mb + i) = o;
}

// ---------------------------------------------------------------
// Small reg-staged MFMA GEMM (Wov = Wo @ Wv, 1024^3).
// ---------------------------------------------------------------
__global__ __launch_bounds__(256) void gemm_wov(
    const unsigned short* __restrict__ A,
    const unsigned short* __restrict__ Bw,
    unsigned short* __restrict__ Cout,
    int M, int N, int K)
{
  __shared__ unsigned short Asm[128][72];
  __shared__ unsigned short Bsm[64][72];
  const int t = threadIdx.x;
  const int lane = t & 63, w = t >> 6;
  const int wm = w >> 1, wn = w & 1;
  const int bm = blockIdx.y * 128, bn = blockIdx.x * 64;

  f32x4 acc[4][2] = {};

  const int sr  = t >> 3;
  const int skq = (t & 7) * 8;
  const int fr  = lane & 15;
  const int kf  = (lane >> 4) * 8;

  for (int k0 = 0; k0 < K; k0 += 64) {
    const u16x8 a0 = *(const u16x8*)(A  + (size_t)(bm + sr)      * K + k0 + skq);
    const u16x8 a1 = *(const u16x8*)(A  + (size_t)(bm + sr + 32) * K + k0 + skq);
    const u16x8 a2 = *(const u16x8*)(A  + (size_t)(bm + sr + 64) * K + k0 + skq);
    const u16x8 a3 = *(const u16x8*)(A  + (size_t)(bm + sr + 96) * K + k0 + skq);
    const u16x8 b0 = *(const u16x8*)(Bw + (size_t)(bn + sr)      * K + k0 + skq);
    const u16x8 b1 = *(const u16x8*)(Bw + (size_t)(bn + sr + 32) * K + k0 + skq);
    __syncthreads();
    *(u16x8*)&Asm[sr][skq]      = a0;
    *(u16x8*)&Asm[sr + 32][skq] = a1;
    *(u16x8*)&Asm[sr + 64][skq] = a2;
    *(u16x8*)&Asm[sr + 96][skq] = a3;
    *(u16x8*)&Bsm[sr][skq]      = b0;
    *(u16x8*)&Bsm[sr + 32][skq] = b1;
    __syncthreads();

    s16x8 af[4][2], bf[2][2];
    #pragma unroll
    for (int fm = 0; fm < 4; ++fm)
      #pragma unroll
      for (int kk = 0; kk < 2; ++kk)
        af[fm][kk] = *(const s16x8*)&Asm[wm * 64 + fm * 16 + fr][kf + kk * 32];
    #pragma unroll
    for (int fn = 0; fn < 2; ++fn)
      #pragma unroll
      for (int kk = 0; kk < 2; ++kk)
        bf[fn][kk] = *(const s16x8*)&Bsm[wn * 32 + fn * 16 + fr][kf + kk * 32];

    #pragma unroll
    for (int fm = 0; fm < 4; ++fm)
      #pragma unroll
      for (int fn = 0; fn < 2; ++fn) {
        acc[fm][fn] = __builtin_amdgcn_mfma_f32_16x16x32_bf16(af[fm][0], bf[fn][0], acc[fm][fn], 0, 0, 0);
        acc[fm][fn] = __builtin_amdgcn_mfma_f32_16x16x32_bf16(af[fm][1], bf[fn][1], acc[fm][fn], 0, 0, 0);
      }
  }

  const int rg = (lane >> 4) * 4;
  #pragma unroll
  for (int fm = 0; fm < 4; ++fm)
    #pragma unroll
    for (int fn = 0; fn < 2; ++fn) {
      const int col = bn + wn * 32 + fn * 16 + fr;
      #pragma unroll
      for (int r = 0; r < 4; ++r) {
        const int row = bm + wm * 64 + fm * 16 + rg + r;
        Cout[(size_t)row * N + col] = f2bf(acc[fm][fn][r]);
      }
    }
}

// ---------------------------------------------------------------
// Fused projection GEMM (m97 structure, unchanged from r5).
// ---------------------------------------------------------------
__global__ __launch_bounds__(256, 3) void gemm_big(
    const unsigned short* __restrict__ objA,
    const unsigned short* __restrict__ crossA,
    const unsigned short* __restrict__ Wall,   // [3072][1024]
    const float* __restrict__ ball,            // [3072]
    unsigned short* __restrict__ Qo,           // [4096][1024]
    unsigned short* __restrict__ Ko,           // [4096][1024]
    unsigned short* __restrict__ VWt)          // [B*1024][256]
{
  __shared__ unsigned short Asm[128 * 64];
  __shared__ unsigned short Bsm[128 * 64];
  const int t = threadIdx.x;
  const int w = t >> 6, lane = t & 63;
  const int wm = w >> 1, wn = w & 1;
  const int bn = blockIdx.x * 128;
  const int bm = blockIdx.y * 128;
  const unsigned short* Ag = (bn < 1024) ? objA : crossA;

  const int srow = lane >> 3;
  const int skel = (lane & 7) * 8;
  const int fr = lane & 15, kf = (lane >> 4) * 8;

  f32x4 acc[4][4] = {};

  for (int k0 = 0; k0 < 1024; k0 += 64) {
    if (k0) __syncthreads();
    #pragma unroll
    for (int i = 0; i < 4; ++i) {
      const int c = i * 4 + w;
      const int r = c * 8 + srow;
      gload16(Ag   + (size_t)(bm + r) * 1024 + k0 + skel, &Asm[c * 512]);
      gload16(Wall + (size_t)(bn + r) * 1024 + k0 + skel, &Bsm[c * 512]);
    }
    __syncthreads();
    #pragma unroll
    for (int kk = 0; kk < 2; ++kk) {
      s16x8 af[4], bf[4];
      #pragma unroll
      for (int fm = 0; fm < 4; ++fm)
        af[fm] = *(const s16x8*)&Asm[(wm * 64 + fm * 16 + fr) * 64 + kk * 32 + kf];
      #pragma unroll
      for (int fn = 0; fn < 4; ++fn)
        bf[fn] = *(const s16x8*)&Bsm[(wn * 64 + fn * 16 + fr) * 64 + kk * 32 + kf];
      #pragma unroll
      for (int fm = 0; fm < 4; ++fm)
        #pragma unroll
        for (int fn = 0; fn < 4; ++fn)
          acc[fm][fn] = __builtin_amdgcn_mfma_f32_16x16x32_bf16(af[fm], bf[fn], acc[fm][fn], 0, 0, 0);
    }
  }

  const int rg = (lane >> 4) * 4;
  const int mode = bn >> 10;
  #pragma unroll
  for (int fm = 0; fm < 4; ++fm) {
    #pragma unroll
    for (int fn = 0; fn < 4; ++fn) {
      const int col  = bn + wn * 64 + fn * 16 + fr;
      const int cl   = col & 1023;
      const float bb = ball[col];
      const int row0 = bm + wm * 64 + fm * 16 + rg;
      if (mode == 0) {
        #pragma unroll
        for (int r = 0; r < 4; ++r)
          Qo[(size_t)(row0 + r) * 1024 + cl] = f2bf(acc[fm][fn][r] + bb);
      } else if (mode == 1) {
        #pragma unroll
        for (int r = 0; r < 4; ++r)
          Ko[(size_t)(row0 + r) * 1024 + cl] = f2bf(acc[fm][fn][r] + bb);
      } else {
        const int bidx = row0 >> 8, tok = row0 & 255;
        ushort4 u;
        u.x = f2bf(acc[fm][fn][0] + bb);
        u.y = f2bf(acc[fm][fn][1] + bb);
        u.z = f2bf(acc[fm][fn][2] + bb);
        u.w = f2bf(acc[fm][fn][3] + bb);
        *(ushort4*)(VWt + ((size_t)bidx * 1024 + cl) * 256 + tok) = u;
      }
    }
  }
}

// ---------------------------------------------------------------
// MFMA attention v3. Block = (b, qtile-of-16): 256 blocks x 1024 thr
// (16 waves, wave = one head). S^T = mfma(K, Q); P stays in regs
// (shuffle redistribution for PV); attm head-sum via LDS f32 atomics
// (block-local -> no Pb buffer, no attm_reduce kernel).
// XCD map: bid = ((b>>3)*16 + qt)*8 + (b&7)  -> both b's of a residue
// class live on one XCD => per-XCD working set ~3.6MB <= 4MB L2.
// ---------------------------------------------------------------
__global__ __launch_bounds__(1024, 4) void attn_mfma(
    const unsigned short* __restrict__ Qg,    // [B*256][1024] bf16, pre-scaled 1/8
    const unsigned short* __restrict__ Kg,    // [B*256][1024] bf16
    const unsigned short* __restrict__ VWt,   // [B*1024][256] bf16 ([b][h*64+d][k])
    const float* __restrict__ mb,             // [B][256][256] masked bias
    const float* __restrict__ bo,
    float* __restrict__ outp, float* __restrict__ attm)
{
  const int t = threadIdx.x;
  const int w = t >> 6, lane = t & 63;
  const int fr = lane & 15, grp = lane >> 4;
  const int bid = blockIdx.x;
  const int x = bid & 7, j = bid >> 3;
  const int b  = ((j >> 4) << 3) | x;   // 2 b's per XCD residue class
  const int qt = j & 15;
  const int h  = w;
  const int q0 = qt * 16;

  __shared__ float attm_s[256][20];     // [k][q] stride 20 -> 2-way conflicts only

  // zero the attm accumulator
  float* as_flat = &attm_s[0][0];
  for (int i = t; i < 5120; i += 1024) as_flat[i] = 0.f;
  __syncthreads();

  // ---- Q B-frags (n = q = fr, kdim = d) ----
  const unsigned short* qp = Qg + ((size_t)(b * 256 + q0 + fr)) * 1024 + h * 64 + grp * 8;
  const s16x8 qf0 = *(const s16x8*)qp;
  const s16x8 qf1 = *(const s16x8*)(qp + 32);

  // ---- S^T = K Q^T: 4-nf batches, 2-deep ping-pong, mask folded in ----
  const unsigned short* kp = Kg + ((size_t)(b * 256 + fr)) * 1024 + h * 64 + grp * 8;
  const float* mbp = mb + ((size_t)(b * 256 + q0 + fr)) * 256 + grp * 4;

  f32x4 s[16];
  #pragma unroll
  for (int nf = 0; nf < 16; ++nf) s[nf] = (f32x4){0.f, 0.f, 0.f, 0.f};

  s16x8 kA[8], kB[8];
  float4 mA[4], mB[4];
  float mx = -3e38f;

#define LOADB(KF, MF, nb)                                                    \
  { _Pragma("unroll") for (int i = 0; i < 4; ++i) {                          \
      KF[2*i]   = *(const s16x8*)(kp + (size_t)((nb)*4 + i) * 16384);        \
      KF[2*i+1] = *(const s16x8*)(kp + (size_t)((nb)*4 + i) * 16384 + 32);   \
      MF[i]     = *(const float4*)(mbp + ((nb)*4 + i) * 16); } }
#define MFMAB(KF, nb)                                                        \
  { _Pragma("unroll") for (int i = 0; i < 4; ++i) {                          \
      s[(nb)*4+i] = __builtin_amdgcn_mfma_f32_16x16x32_bf16(KF[2*i],   qf0, s[(nb)*4+i], 0, 0, 0); \
      s[(nb)*4+i] = __builtin_amdgcn_mfma_f32_16x16x32_bf16(KF[2*i+1], qf1, s[(nb)*4+i], 0, 0, 0); } }
#define MASKB(MF, nb)                                                        \
  { _Pragma("unroll") for (int i = 0; i < 4; ++i) {                          \
      _Pragma("unroll") for (int r = 0; r < 4; ++r) {                        \
        const float m = ((const float*)&MF[i])[r];                           \
        const float v = (m > -1e14f) ? s[(nb)*4+i][r] + m : m;               \
        s[(nb)*4+i][r] = v; mx = fmaxf(mx, v); } } }

  LOADB(kA, mA, 0); LOADB(kB, mB, 1); MFMAB(kA, 0);
  MASKB(mA, 0);     LOADB(kA, mA, 2); MFMAB(kB, 1);
  MASKB(mB, 1);     LOADB(kB, mB, 3); MFMAB(kA, 2);
  MASKB(mA, 2);     LOADB(kA, mA, 4); MFMAB(kB, 3);
  MASKB(mB, 3);     LOADB(kB, mB, 5); MFMAB(kA, 4);
  MASKB(mA, 4);     LOADB(kA, mA, 6); MFMAB(kB, 5);
  MASKB(mB, 5);     LOADB(kB, mB, 7); MFMAB(kA, 6);
  MASKB(mA, 6);     MFMAB(kB, 7);     MASKB(mB, 7);
#undef LOADB
#undef MFMAB
#undef MASKB

  // ---- softmax (row q = fr, spread over grp lanes) ----
  mx = fmaxf(mx, __shfl_xor(mx, 16));
  mx = fmaxf(mx, __shfl_xor(mx, 32));
  float sm = 0.f;
  #pragma unroll
  for (int nf = 0; nf < 16; ++nf)
    #pragma unroll
    for (int r = 0; r < 4; ++r) {
      const float e = __expf(s[nf][r] - mx);
      s[nf][r] = e;
      sm += e;
    }
  sm += __shfl_xor(sm, 16);
  sm += __shfl_xor(sm, 32);
  const float inv = 1.f / sm;

  // ---- attm: head-sum via LDS atomics (lane holds P[k=16nf+4grp+r][q=fr]) ----
  const float sc = inv * 0.0625f;
  #pragma unroll
  for (int nf = 0; nf < 16; ++nf)
    #pragma unroll
    for (int r = 0; r < 4; ++r)
      atomicAdd(&attm_s[nf * 16 + grp * 4 + r][fr], s[nf][r] * sc);

  // ---- pack P -> bf16 pairs in registers ----
  uint2 u2[16];
  #pragma unroll
  for (int nf = 0; nf < 16; ++nf) {
    const unsigned lo = (unsigned)f2bf(s[nf][0] * inv) | ((unsigned)f2bf(s[nf][1] * inv) << 16);
    const unsigned hi = (unsigned)f2bf(s[nf][2] * inv) | ((unsigned)f2bf(s[nf][3] * inv) << 16);
    u2[nf] = make_uint2(lo, hi);
  }

  // ---- PV: pf via shuffles, vf from global (L2-resident VW slice) ----
  f32x4 o[4];
  #pragma unroll
  for (int nf = 0; nf < 4; ++nf) o[nf] = (f32x4){0.f, 0.f, 0.f, 0.f};
  const int srcA = fr + ((grp & 1) << 5);
  const int srcB = srcA + 16;
  const bool hiSel = (grp & 2);
  const unsigned short* vp = VWt + ((size_t)(b * 16 + h) * 64 + fr) * 256 + grp * 8;
  #pragma unroll
  for (int ks = 0; ks < 8; ++ks) {
    const int aLx = __shfl((int)u2[2 * ks].x,     srcA, 64);
    const int aLy = __shfl((int)u2[2 * ks].y,     srcA, 64);
    const int bLx = __shfl((int)u2[2 * ks].x,     srcB, 64);
    const int bLy = __shfl((int)u2[2 * ks].y,     srcB, 64);
    const int aHx = __shfl((int)u2[2 * ks + 1].x, srcA, 64);
    const int aHy = __shfl((int)u2[2 * ks + 1].y, srcA, 64);
    const int bHx = __shfl((int)u2[2 * ks + 1].x, srcB, 64);
    const int bHy = __shfl((int)u2[2 * ks + 1].y, srcB, 64);
    union { int4 i; s16x8 v; } pf;
    pf.i = hiSel ? make_int4(aHx, aHy, bHx, bHy) : make_int4(aLx, aLy, bLx, bLy);
    #pragma unroll
    for (int nf = 0; nf < 4; ++nf) {
      const s16x8 vf = *(const s16x8*)(vp + (size_t)nf * 4096 + ks * 32);
      o[nf] = __builtin_amdgcn_mfma_f32_16x16x32_bf16(pf.v, vf, o[nf], 0, 0, 0);
    }
  }

  // ---- epilogue: + bo, store f32 (lane holds O[q=grp*4+r][d=nf*16+fr]) ----
  #pragma unroll
  for (int nf = 0; nf < 4; ++nf) {
    const float bb = bo[h * 64 + nf * 16 + fr];
    #pragma unroll
    for (int r = 0; r < 4; ++r)
      outp[((size_t)b * 256 + q0 + grp * 4 + r) * 1024 + h * 64 + nf * 16 + fr]
          = o[nf][r] + bb;
  }

  // ---- attm writeout (all heads accumulated) ----
  __syncthreads();
  {
    const int q = t >> 6, k4 = (t & 63) * 4;
    float4 v;
    v.x = attm_s[k4 + 0][q];
    v.y = attm_s[k4 + 1][q];
    v.z = attm_s[k4 + 2][q];
    v.w = attm_s[k4 + 3][q];
    *(float4*)(attm + ((size_t)b * 256 + q0 + q) * 256 + k4) = v;
  }
}

// ---------------------------------------------------------------
extern "C" void kernel_launch(void* const* d_in, const int* in_sizes, int n_in,
                              void* d_out, int out_size, void* d_ws, size_t ws_size,
                              hipStream_t stream)
{
  const float* obj   = (const float*)d_in[0];
  const float* cross = (const float*)d_in[1];
  const int*   adj   = (const int*)d_in[2];
  const float* lab   = (const float*)d_in[3];
  const float* Wq    = (const float*)d_in[4];
  const float* bq    = (const float*)d_in[5];
  const float* Wk    = (const float*)d_in[6];
  const float* bk    = (const float*)d_in[7];
  const float* Wv    = (const float*)d_in[8];
  const float* bv    = (const float*)d_in[9];
  const float* Wo    = (const float*)d_in[10];
  const float* bo    = (const float*)d_in[11];

  float* out  = (float*)d_out;
  float* attm = out + (size_t)16 * 256 * 1024;

  // workspace layout (bytes)
  char* ws = (char*)d_ws;
  unsigned short* obj_bf   = (unsigned short*)(ws + 0);          // 8 MB (mbuf aliases later)
  unsigned short* cross_bf = (unsigned short*)(ws + 8388608);    // 8 MB
  unsigned short* Qbf      = (unsigned short*)(ws + 16777216);   // 8 MB
  unsigned short* Kbf      = (unsigned short*)(ws + 25165824);   // 8 MB
  unsigned short* VWt      = (unsigned short*)(ws + 33554432);   // 8 MB [B*1024][256]
  unsigned short* Wall     = (unsigned short*)(ws + 41943040);   // 6 MB [3072][1024]
  unsigned short* Wo_bf    = (unsigned short*)(ws + 48234496);   // 2 MB
  unsigned short* Wvt_bf   = (unsigned short*)(ws + 50331648);   // 2 MB (ball aliases after Wov gemm)
  float*          ball     = (float*)(ws + 50331648);            // 12 KB
  float*          mbuf     = (float*)obj_bf;                     // 4 MB (after gemm_big)

  // fp32 -> bf16 conversions (Wq pre-scaled by 1/8 — exact in bf16)
  cvt_bf16<<<4096, 256, 0, stream>>>(obj,   obj_bf,   4194304, 1.f);
  cvt_bf16<<<4096, 256, 0, stream>>>(cross, cross_bf, 4194304, 1.f);
  cvt_bf16<<<1024, 256, 0, stream>>>(Wq, Wall,           1048576, 0.125f);
  cvt_bf16<<<1024, 256, 0, stream>>>(Wk, Wall + 1048576, 1048576, 1.f);
  cvt_bf16<<<1024, 256, 0, stream>>>(Wo, Wo_bf,          1048576, 1.f);
  tcvt_bf16<<<dim3(32, 32), 256, 0, stream>>>(Wv, Wvt_bf, 1024, 1024);

  // Wov = Wo @ Wv  -> Wall rows [2048, 3072)
  gemm_wov<<<dim3(16, 8), 256, 0, stream>>>(
      Wo_bf, Wvt_bf, Wall + 2097152, 1024, 1024, 1024);

  // bias vector [0.125*bq | bk | bov]
  bias_prep<<<4, 256, 0, stream>>>(bq, bk, ball);
  bov_kernel<<<256, 256, 0, stream>>>(Wo, bv, ball + 2048);

  // fused [Q | K | VW] projection
  gemm_big<<<dim3(24, 32), 256, 0, stream>>>(
      obj_bf, cross_bf, Wall, ball, Qbf, Kbf, VWt);

  // obj_bf dead -> masked-bias table
  mb_prep<<<1024, 256, 0, stream>>>(adj, lab, mbuf);

  // fused attention + attm (no Pb, no attm_reduce)
  attn_mfma<<<256, 1024, 0, stream>>>(
      Qbf, Kbf, VWt, mbuf, bo, out, attm);
}

// Round 8
// 129.373 us; speedup vs baseline: 1.5188x; 1.5188x over previous
//
#include <hip/hip_runtime.h>

#define NEGF -9e15f

typedef __attribute__((ext_vector_type(8))) unsigned short u16x8;
typedef __attribute__((ext_vector_type(8))) short          s16x8;
typedef __attribute__((ext_vector_type(4))) float          f32x4;

// ---------- bf16 helpers (RTN-even) ----------
__device__ __forceinline__ unsigned short f2bf(float x) {
  union { float f; unsigned int u; } c; c.f = x;
  unsigned int r = c.u + 0x7fffu + ((c.u >> 16) & 1u);
  return (unsigned short)(r >> 16);
}
__device__ __forceinline__ float bf2f(unsigned short v) {
  union { float f; unsigned int u; } c; c.u = ((unsigned int)v) << 16;
  return c.f;
}

// ---------- async global->LDS, 16B per lane (wave-uniform LDS base) ----------
__device__ __forceinline__ void gload16(const void* g, void* l) {
  __builtin_amdgcn_global_load_lds(
      (const __attribute__((address_space(1))) unsigned int*)g,
      (__attribute__((address_space(3))) unsigned int*)l, 16, 0, 0);
}

// ---------- fp32 -> bf16 elementwise (optional scale) ----------
__global__ __launch_bounds__(256) void cvt_bf16(
    const float* __restrict__ in, unsigned short* __restrict__ out, int n, float scale)
{
  const int i = (blockIdx.x * 256 + threadIdx.x) * 4;
  if (i < n) {
    const float4 v = *(const float4*)(in + i);
    ushort4 o;
    o.x = f2bf(v.x * scale); o.y = f2bf(v.y * scale);
    o.z = f2bf(v.z * scale); o.w = f2bf(v.w * scale);
    *(ushort4*)(out + i) = o;
  }
}

// ---------- fp32 -> bf16 transposed (out[c][r] = in[r][c]) ----------
__global__ __launch_bounds__(256) void tcvt_bf16(
    const float* __restrict__ in, unsigned short* __restrict__ out, int R, int C)
{
  __shared__ float tile[32][33];
  const int bc = blockIdx.x * 32, br = blockIdx.y * 32;
  const int tx = threadIdx.x & 31, ty8 = threadIdx.x >> 5;
  #pragma unroll
  for (int j = 0; j < 32; j += 8)
    tile[ty8 + j][tx] = in[(size_t)(br + ty8 + j) * C + bc + tx];
  __syncthreads();
  #pragma unroll
  for (int j = 0; j < 32; j += 8)
    out[(size_t)(bc + ty8 + j) * R + br + tx] = f2bf(tile[tx][ty8 + j]);
}

// bov[g] = sum_f Wo[g][f] * bv[f]
__global__ __launch_bounds__(256) void bov_kernel(
    const float* __restrict__ Wo, const float* __restrict__ bv,
    float* __restrict__ bov)
{
  const int g    = blockIdx.x * 4 + (threadIdx.x >> 6);
  const int lane = threadIdx.x & 63;
  float acc = 0.f;
  for (int f = lane; f < 1024; f += 64)
    acc = fmaf(Wo[(size_t)g * 1024 + f], bv[f], acc);
  #pragma unroll
  for (int off = 32; off > 0; off >>= 1) acc += __shfl_down(acc, off);
  if (lane == 0) bov[g] = acc;
}

// ball[0:1024) = 0.125*bq ; ball[1024:2048) = bk
__global__ __launch_bounds__(256) void bias_prep(
    const float* __restrict__ bq, const float* __restrict__ bk,
    float* __restrict__ ball)
{
  const int i = blockIdx.x * 256 + threadIdx.x;
  ball[i]        = 0.125f * bq[i];
  ball[1024 + i] = bk[i];
}

// mb[i] = adj[i] > 0 ? lab[i] : NEG
__global__ __launch_bounds__(256) void mb_prep(
    const int* __restrict__ adj, const float* __restrict__ lab,
    float* __restrict__ mb)
{
  const int i = (blockIdx.x * 256 + threadIdx.x) * 4;
  const int4   a = *(const int4*)(adj + i);
  const float4 l = *(const float4*)(lab + i);
  float4 o;
  o.x = a.x > 0 ? l.x : NEGF;
  o.y = a.y > 0 ? l.y : NEGF;
  o.z = a.z > 0 ? l.z : NEGF;
  o.w = a.w > 0 ? l.w : NEGF;
  *(float4*)(mb + i) = o;
}

// ---------------------------------------------------------------
// Small reg-staged MFMA GEMM (Wov = Wo @ Wv, 1024^3).
// ---------------------------------------------------------------
__global__ __launch_bounds__(256) void gemm_wov(
    const unsigned short* __restrict__ A,
    const unsigned short* __restrict__ Bw,
    unsigned short* __restrict__ Cout,
    int M, int N, int K)
{
  __shared__ unsigned short Asm[128][72];
  __shared__ unsigned short Bsm[64][72];
  const int t = threadIdx.x;
  const int lane = t & 63, w = t >> 6;
  const int wm = w >> 1, wn = w & 1;
  const int bm = blockIdx.y * 128, bn = blockIdx.x * 64;

  f32x4 acc[4][2] = {};

  const int sr  = t >> 3;
  const int skq = (t & 7) * 8;
  const int fr  = lane & 15;
  const int kf  = (lane >> 4) * 8;

  for (int k0 = 0; k0 < K; k0 += 64) {
    const u16x8 a0 = *(const u16x8*)(A  + (size_t)(bm + sr)      * K + k0 + skq);
    const u16x8 a1 = *(const u16x8*)(A  + (size_t)(bm + sr + 32) * K + k0 + skq);
    const u16x8 a2 = *(const u16x8*)(A  + (size_t)(bm + sr + 64) * K + k0 + skq);
    const u16x8 a3 = *(const u16x8*)(A  + (size_t)(bm + sr + 96) * K + k0 + skq);
    const u16x8 b0 = *(const u16x8*)(Bw + (size_t)(bn + sr)      * K + k0 + skq);
    const u16x8 b1 = *(const u16x8*)(Bw + (size_t)(bn + sr + 32) * K + k0 + skq);
    __syncthreads();
    *(u16x8*)&Asm[sr][skq]      = a0;
    *(u16x8*)&Asm[sr + 32][skq] = a1;
    *(u16x8*)&Asm[sr + 64][skq] = a2;
    *(u16x8*)&Asm[sr + 96][skq] = a3;
    *(u16x8*)&Bsm[sr][skq]      = b0;
    *(u16x8*)&Bsm[sr + 32][skq] = b1;
    __syncthreads();

    s16x8 af[4][2], bf[2][2];
    #pragma unroll
    for (int fm = 0; fm < 4; ++fm)
      #pragma unroll
      for (int kk = 0; kk < 2; ++kk)
        af[fm][kk] = *(const s16x8*)&Asm[wm * 64 + fm * 16 + fr][kf + kk * 32];
    #pragma unroll
    for (int fn = 0; fn < 2; ++fn)
      #pragma unroll
      for (int kk = 0; kk < 2; ++kk)
        bf[fn][kk] = *(const s16x8*)&Bsm[wn * 32 + fn * 16 + fr][kf + kk * 32];

    #pragma unroll
    for (int fm = 0; fm < 4; ++fm)
      #pragma unroll
      for (int fn = 0; fn < 2; ++fn) {
        acc[fm][fn] = __builtin_amdgcn_mfma_f32_16x16x32_bf16(af[fm][0], bf[fn][0], acc[fm][fn], 0, 0, 0);
        acc[fm][fn] = __builtin_amdgcn_mfma_f32_16x16x32_bf16(af[fm][1], bf[fn][1], acc[fm][fn], 0, 0, 0);
      }
  }

  const int rg = (lane >> 4) * 4;
  #pragma unroll
  for (int fm = 0; fm < 4; ++fm)
    #pragma unroll
    for (int fn = 0; fn < 2; ++fn) {
      const int col = bn + wn * 32 + fn * 16 + fr;
      #pragma unroll
      for (int r = 0; r < 4; ++r) {
        const int row = bm + wm * 64 + fm * 16 + rg + r;
        Cout[(size_t)row * N + col] = f2bf(acc[fm][fn][r]);
      }
    }
}

// ---------------------------------------------------------------
// Fused projection GEMM (m97 structure, unchanged from r5).
// ---------------------------------------------------------------
__global__ __launch_bounds__(256, 3) void gemm_big(
    const unsigned short* __restrict__ objA,
    const unsigned short* __restrict__ crossA,
    const unsigned short* __restrict__ Wall,   // [3072][1024]
    const float* __restrict__ ball,            // [3072]
    unsigned short* __restrict__ Qo,           // [4096][1024]
    unsigned short* __restrict__ Ko,           // [4096][1024]
    unsigned short* __restrict__ VWt)          // [B*1024][256]
{
  __shared__ unsigned short Asm[128 * 64];
  __shared__ unsigned short Bsm[128 * 64];
  const int t = threadIdx.x;
  const int w = t >> 6, lane = t & 63;
  const int wm = w >> 1, wn = w & 1;
  const int bn = blockIdx.x * 128;
  const int bm = blockIdx.y * 128;
  const unsigned short* Ag = (bn < 1024) ? objA : crossA;

  const int srow = lane >> 3;
  const int skel = (lane & 7) * 8;
  const int fr = lane & 15, kf = (lane >> 4) * 8;

  f32x4 acc[4][4] = {};

  for (int k0 = 0; k0 < 1024; k0 += 64) {
    if (k0) __syncthreads();
    #pragma unroll
    for (int i = 0; i < 4; ++i) {
      const int c = i * 4 + w;
      const int r = c * 8 + srow;
      gload16(Ag   + (size_t)(bm + r) * 1024 + k0 + skel, &Asm[c * 512]);
      gload16(Wall + (size_t)(bn + r) * 1024 + k0 + skel, &Bsm[c * 512]);
    }
    __syncthreads();
    #pragma unroll
    for (int kk = 0; kk < 2; ++kk) {
      s16x8 af[4], bf[4];
      #pragma unroll
      for (int fm = 0; fm < 4; ++fm)
        af[fm] = *(const s16x8*)&Asm[(wm * 64 + fm * 16 + fr) * 64 + kk * 32 + kf];
      #pragma unroll
      for (int fn = 0; fn < 4; ++fn)
        bf[fn] = *(const s16x8*)&Bsm[(wn * 64 + fn * 16 + fr) * 64 + kk * 32 + kf];
      #pragma unroll
      for (int fm = 0; fm < 4; ++fm)
        #pragma unroll
        for (int fn = 0; fn < 4; ++fn)
          acc[fm][fn] = __builtin_amdgcn_mfma_f32_16x16x32_bf16(af[fm], bf[fn], acc[fm][fn], 0, 0, 0);
    }
  }

  const int rg = (lane >> 4) * 4;
  const int mode = bn >> 10;
  #pragma unroll
  for (int fm = 0; fm < 4; ++fm) {
    #pragma unroll
    for (int fn = 0; fn < 4; ++fn) {
      const int col  = bn + wn * 64 + fn * 16 + fr;
      const int cl   = col & 1023;
      const float bb = ball[col];
      const int row0 = bm + wm * 64 + fm * 16 + rg;
      if (mode == 0) {
        #pragma unroll
        for (int r = 0; r < 4; ++r)
          Qo[(size_t)(row0 + r) * 1024 + cl] = f2bf(acc[fm][fn][r] + bb);
      } else if (mode == 1) {
        #pragma unroll
        for (int r = 0; r < 4; ++r)
          Ko[(size_t)(row0 + r) * 1024 + cl] = f2bf(acc[fm][fn][r] + bb);
      } else {
        const int bidx = row0 >> 8, tok = row0 & 255;
        ushort4 u;
        u.x = f2bf(acc[fm][fn][0] + bb);
        u.y = f2bf(acc[fm][fn][1] + bb);
        u.z = f2bf(acc[fm][fn][2] + bb);
        u.w = f2bf(acc[fm][fn][3] + bb);
        *(ushort4*)(VWt + ((size_t)bidx * 1024 + cl) * 256 + tok) = u;
      }
    }
  }
}

// ---------------------------------------------------------------
// MFMA attention v4 (r6 structure + K staged in LDS via DMA).
// Grid 1024 (qt=bid>>8), 256 threads = 4 waves; wave owns 16 q rows.
// K and VW both DMA'd to LDS with pre-swizzled source columns
// (byte ^= (row&7)<<4); QK^T + PV read LDS conflict-free.
// P in regs -> Pb (bf16) + shuffle redistribution for PV.
// LDS 64KB -> 2 blocks/CU.
// ---------------------------------------------------------------
__global__ __launch_bounds__(256, 2) void attn_mfma(
    const unsigned short* __restrict__ Qg,    // [B*256][1024] bf16, pre-scaled 1/8
    const unsigned short* __restrict__ Kg,    // [B*256][1024] bf16
    const unsigned short* __restrict__ VWt,   // [B*1024][256] bf16 ([b][h*64+d][k])
    const float* __restrict__ mb,             // [B][256][256] masked bias
    const float* __restrict__ bo,
    float* __restrict__ outp, unsigned short* __restrict__ Pb)
{
  const int t = threadIdx.x;
  const int w = t >> 6, lane = t & 63;
  const int fr = lane & 15, grp = lane >> 4;
  const int bid = blockIdx.x;
  const int qt = bid >> 8, hb = bid & 255;
  const int h = hb & 15, b = hb >> 4;
  const int q0 = qt * 64 + w * 16;

  __shared__ __align__(16) unsigned short Ks[256 * 64];    // 32 KB [k_row][d]
  __shared__ __align__(16) unsigned short VWs[64 * 256];   // 32 KB [d][k]

  // ---- DMA K slice (b,h): rows 128B, source col pre-swizzled ----
  {
    const unsigned short* kb = Kg + (size_t)(b * 256) * 1024 + h * 64;
    const int colb = (lane & 7) * 16;                      // byte col in 128B row
    #pragma unroll
    for (int c = 0; c < 8; ++c) {
      const int row = c * 32 + w * 8 + (lane >> 3);
      const int sb  = colb ^ ((row & 7) << 4);
      gload16(kb + (size_t)row * 1024 + (sb >> 1), (char*)Ks + c * 4096 + w * 1024);
    }
  }
  // ---- DMA VW slice (b,h): rows 512B, source col pre-swizzled ----
  {
    const unsigned short* vwb = VWt + (size_t)(b * 16 + h) * 16384;
    const int xb = (lane & 31) * 16;
    #pragma unroll
    for (int c = 0; c < 8; ++c) {
      const int row = c * 8 + w * 2 + (lane >> 5);
      const int sb  = xb ^ ((row & 7) << 4);
      gload16(vwb + row * 256 + (sb >> 1), (char*)VWs + c * 4096 + w * 1024);
    }
  }

  // ---- Q B-frags (global, L2-hot) ----
  const unsigned short* qp = Qg + ((size_t)(b * 256 + q0 + fr)) * 1024 + h * 64 + grp * 8;
  const s16x8 qf0 = *(const s16x8*)qp;
  const s16x8 qf1 = *(const s16x8*)(qp + 32);

  __syncthreads();   // drains DMA (vmcnt 0) -> Ks/VWs ready

  // ---- S^T = K Q^T from LDS, mb from global, mask folded in ----
  const float* mbp = mb + ((size_t)(b * 256 + q0 + fr)) * 256 + grp * 4;
  const int colA = (grp * 16) ^ ((fr & 7) << 4);   // swizzled col for this lane

  f32x4 s[16];
  #pragma unroll
  for (int nf = 0; nf < 16; ++nf) s[nf] = (f32x4){0.f, 0.f, 0.f, 0.f};

  s16x8 kA[8], kB[8];
  float4 mA[4], mB[4];
  float mx = -3e38f;

#define LOADB(KF, MF, nb)                                                    \
  { _Pragma("unroll") for (int i = 0; i < 4; ++i) {                          \
      const char* rp = (const char*)Ks + (((nb)*4 + i) * 16 + fr) * 128;     \
      KF[2*i]   = *(const s16x8*)(rp + colA);                                \
      KF[2*i+1] = *(const s16x8*)(rp + (colA ^ 64));                         \
      MF[i]     = *(const float4*)(mbp + ((nb)*4 + i) * 16); } }
#define MFMAB(KF, nb)                                                        \
  { _Pragma("unroll") for (int i = 0; i < 4; ++i) {                          \
      s[(nb)*4+i] = __builtin_amdgcn_mfma_f32_16x16x32_bf16(KF[2*i],   qf0, s[(nb)*4+i], 0, 0, 0); \
      s[(nb)*4+i] = __builtin_amdgcn_mfma_f32_16x16x32_bf16(KF[2*i+1], qf1, s[(nb)*4+i], 0, 0, 0); } }
#define MASKB(MF, nb)                                                        \
  { _Pragma("unroll") for (int i = 0; i < 4; ++i) {                          \
      _Pragma("unroll") for (int r = 0; r < 4; ++r) {                        \
        const float m = ((const float*)&MF[i])[r];                           \
        const float v = (m > -1e14f) ? s[(nb)*4+i][r] + m : m;               \
        s[(nb)*4+i][r] = v; mx = fmaxf(mx, v); } } }

  LOADB(kA, mA, 0); LOADB(kB, mB, 1); MFMAB(kA, 0);
  MASKB(mA, 0);     LOADB(kA, mA, 2); MFMAB(kB, 1);
  MASKB(mB, 1);     LOADB(kB, mB, 3); MFMAB(kA, 2);
  MASKB(mA, 2);     LOADB(kA, mA, 4); MFMAB(kB, 3);
  MASKB(mB, 3);     LOADB(kB, mB, 5); MFMAB(kA, 4);
  MASKB(mA, 4);     LOADB(kA, mA, 6); MFMAB(kB, 5);
  MASKB(mB, 5);     LOADB(kB, mB, 7); MFMAB(kA, 6);
  MASKB(mA, 6);     MFMAB(kB, 7);     MASKB(mB, 7);
#undef LOADB
#undef MFMAB
#undef MASKB

  // ---- softmax (row q = fr, spread over grp lanes) ----
  mx = fmaxf(mx, __shfl_xor(mx, 16));
  mx = fmaxf(mx, __shfl_xor(mx, 32));
  float sm = 0.f;
  #pragma unroll
  for (int nf = 0; nf < 16; ++nf)
    #pragma unroll
    for (int r = 0; r < 4; ++r) {
      const float e = __expf(s[nf][r] - mx);
      s[nf][r] = e;
      sm += e;
    }
  sm += __shfl_xor(sm, 16);
  sm += __shfl_xor(sm, 32);
  const float inv = 1.f / sm;

  // ---- pack P -> bf16 pairs in registers ----
  uint2 u2[16];
  #pragma unroll
  for (int nf = 0; nf < 16; ++nf) {
    const unsigned lo = (unsigned)f2bf(s[nf][0] * inv) | ((unsigned)f2bf(s[nf][1] * inv) << 16);
    const unsigned hi = (unsigned)f2bf(s[nf][2] * inv) | ((unsigned)f2bf(s[nf][3] * inv) << 16);
    u2[nf] = make_uint2(lo, hi);
  }

  // ---- Pb store (from regs; k = 16nf + 4grp + 0..3 for row q0+fr) ----
  unsigned short* prow = Pb + (((size_t)(b * 16 + h)) * 256 + q0 + fr) * 256 + grp * 4;
  #pragma unroll
  for (int nf = 0; nf < 16; ++nf)
    *(uint2*)(prow + nf * 16) = u2[nf];

  // ---- PV: pf via shuffles, vf via swizzled LDS reads ----
  f32x4 o[4];
  #pragma unroll
  for (int nf = 0; nf < 4; ++nf) o[nf] = (f32x4){0.f, 0.f, 0.f, 0.f};
  const int srcA = fr + ((grp & 1) << 5);
  const int srcB = srcA + 16;
  const int swz  = (fr & 7) << 4;
  const bool hiSel = (grp & 2);
  #pragma unroll
  for (int ks = 0; ks < 8; ++ks) {
    const int aLx = __shfl((int)u2[2 * ks].x,     srcA, 64);
    const int aLy = __shfl((int)u2[2 * ks].y,     srcA, 64);
    const int bLx = __shfl((int)u2[2 * ks].x,     srcB, 64);
    const int bLy = __shfl((int)u2[2 * ks].y,     srcB, 64);
    const int aHx = __shfl((int)u2[2 * ks + 1].x, srcA, 64);
    const int aHy = __shfl((int)u2[2 * ks + 1].y, srcA, 64);
    const int bHx = __shfl((int)u2[2 * ks + 1].x, srcB, 64);
    const int bHy = __shfl((int)u2[2 * ks + 1].y, srcB, 64);
    union { int4 i; s16x8 v; } pf;
    pf.i = hiSel ? make_int4(aHx, aHy, bHx, bHy) : make_int4(aLx, aLy, bLx, bLy);
    const int cb = (ks * 64 + grp * 16) ^ swz;
    #pragma unroll
    for (int nf = 0; nf < 4; ++nf) {
      const s16x8 vf = *(const s16x8*)((const char*)VWs + (nf * 16 + fr) * 512 + cb);
      o[nf] = __builtin_amdgcn_mfma_f32_16x16x32_bf16(pf.v, vf, o[nf], 0, 0, 0);
    }
  }

  // ---- epilogue: + bo, store f32 (lane holds O[q=grp*4+r][d=nf*16+fr]) ----
  #pragma unroll
  for (int nf = 0; nf < 4; ++nf) {
    const float bb = bo[h * 64 + nf * 16 + fr];
    #pragma unroll
    for (int r = 0; r < 4; ++r)
      outp[((size_t)b * 256 + q0 + grp * 4 + r) * 1024 + h * 64 + nf * 16 + fr]
          = o[nf][r] + bb;
  }
}

// attm[b][q][k] = (1/16) sum_h Pb[b][h][q][k]
__global__ __launch_bounds__(256) void attm_reduce(
    const unsigned short* __restrict__ Pb, float* __restrict__ attm)
{
  const size_t idx = (size_t)blockIdx.x * 256 + threadIdx.x;
  const int    k8  = (int)(idx & 31);
  const size_t bq  = idx >> 5;
  const int    b   = (int)(bq >> 8);
  const int    q   = (int)(bq & 255);
  float s[8] = {};
  const unsigned short* base = Pb + (size_t)b * 1048576 + (size_t)q * 256 + k8 * 8;
  #pragma unroll
  for (int hh = 0; hh < 16; ++hh) {
    const u16x8 p = *(const u16x8*)(base + (size_t)hh * 65536);
    #pragma unroll
    for (int j = 0; j < 8; ++j) s[j] += bf2f(p[j]);
  }
  float* dst = attm + bq * 256 + k8 * 8;
  float4 r0, r1;
  r0.x = s[0] * 0.0625f; r0.y = s[1] * 0.0625f; r0.z = s[2] * 0.0625f; r0.w = s[3] * 0.0625f;
  r1.x = s[4] * 0.0625f; r1.y = s[5] * 0.0625f; r1.z = s[6] * 0.0625f; r1.w = s[7] * 0.0625f;
  *(float4*)dst = r0;
  *(float4*)(dst + 4) = r1;
}

// ---------------------------------------------------------------
extern "C" void kernel_launch(void* const* d_in, const int* in_sizes, int n_in,
                              void* d_out, int out_size, void* d_ws, size_t ws_size,
                              hipStream_t stream)
{
  const float* obj   = (const float*)d_in[0];
  const float* cross = (const float*)d_in[1];
  const int*   adj   = (const int*)d_in[2];
  const float* lab   = (const float*)d_in[3];
  const float* Wq    = (const float*)d_in[4];
  const float* bq    = (const float*)d_in[5];
  const float* Wk    = (const float*)d_in[6];
  const float* bk    = (const float*)d_in[7];
  const float* Wv    = (const float*)d_in[8];
  const float* bv    = (const float*)d_in[9];
  const float* Wo    = (const float*)d_in[10];
  const float* bo    = (const float*)d_in[11];

  float* out  = (float*)d_out;
  float* attm = out + (size_t)16 * 256 * 1024;

  // workspace layout (bytes)
  char* ws = (char*)d_ws;
  unsigned short* obj_bf   = (unsigned short*)(ws + 0);          // 8 MB (mbuf aliases later)
  unsigned short* cross_bf = (unsigned short*)(ws + 8388608);    // 8 MB
  unsigned short* Qbf      = (unsigned short*)(ws + 16777216);   // 8 MB
  unsigned short* Kbf      = (unsigned short*)(ws + 25165824);   // 8 MB
  unsigned short* VWt      = (unsigned short*)(ws + 33554432);   // 8 MB [B*1024][256]
  unsigned short* Wall     = (unsigned short*)(ws + 41943040);   // 6 MB [3072][1024]
  unsigned short* Wo_bf    = (unsigned short*)(ws + 48234496);   // 2 MB
  unsigned short* Wvt_bf   = (unsigned short*)(ws + 50331648);   // 2 MB (ball aliases after Wov gemm)
  float*          ball     = (float*)(ws + 50331648);            // 12 KB
  unsigned short* Pbuf     = (unsigned short*)(ws + 52432896);   // 32 MB
  float*          mbuf     = (float*)obj_bf;                     // 4 MB (after gemm_big)

  // fp32 -> bf16 conversions (Wq pre-scaled by 1/8 — exact in bf16)
  cvt_bf16<<<4096, 256, 0, stream>>>(obj,   obj_bf,   4194304, 1.f);
  cvt_bf16<<<4096, 256, 0, stream>>>(cross, cross_bf, 4194304, 1.f);
  cvt_bf16<<<1024, 256, 0, stream>>>(Wq, Wall,           1048576, 0.125f);
  cvt_bf16<<<1024, 256, 0, stream>>>(Wk, Wall + 1048576, 1048576, 1.f);
  cvt_bf16<<<1024, 256, 0, stream>>>(Wo, Wo_bf,          1048576, 1.f);
  tcvt_bf16<<<dim3(32, 32), 256, 0, stream>>>(Wv, Wvt_bf, 1024, 1024);

  // Wov = Wo @ Wv  -> Wall rows [2048, 3072)
  gemm_wov<<<dim3(16, 8), 256, 0, stream>>>(
      Wo_bf, Wvt_bf, Wall + 2097152, 1024, 1024, 1024);

  // bias vector [0.125*bq | bk | bov]
  bias_prep<<<4, 256, 0, stream>>>(bq, bk, ball);
  bov_kernel<<<256, 256, 0, stream>>>(Wo, bv, ball + 2048);

  // fused [Q | K | VW] projection
  gemm_big<<<dim3(24, 32), 256, 0, stream>>>(
      obj_bf, cross_bf, Wall, ball, Qbf, Kbf, VWt);

  // obj_bf dead -> masked-bias table
  mb_prep<<<1024, 256, 0, stream>>>(adj, lab, mbuf);

  attn_mfma<<<1024, 256, 0, stream>>>(
      Qbf, Kbf, VWt, mbuf, bo, out, Pbuf);
  attm_reduce<<<512, 256, 0, stream>>>(Pbuf, attm);
}

// Round 9
// 123.753 us; speedup vs baseline: 1.5878x; 1.0454x over previous
//
#include <hip/hip_runtime.h>

#define NEGF -9e15f

typedef __attribute__((ext_vector_type(8))) unsigned short u16x8;
typedef __attribute__((ext_vector_type(8))) short          s16x8;
typedef __attribute__((ext_vector_type(4))) float          f32x4;

// ---------- bf16 helpers (RTN-even) ----------
__device__ __forceinline__ unsigned short f2bf(float x) {
  union { float f; unsigned int u; } c; c.f = x;
  unsigned int r = c.u + 0x7fffu + ((c.u >> 16) & 1u);
  return (unsigned short)(r >> 16);
}
__device__ __forceinline__ float bf2f(unsigned short v) {
  union { float f; unsigned int u; } c; c.u = ((unsigned int)v) << 16;
  return c.f;
}

// ---------- async global->LDS, 16B per lane (wave-uniform LDS base) ----------
__device__ __forceinline__ void gload16(const void* g, void* l) {
  __builtin_amdgcn_global_load_lds(
      (const __attribute__((address_space(1))) unsigned int*)g,
      (__attribute__((address_space(3))) unsigned int*)l, 16, 0, 0);
}

// ---------- fused fp32->bf16 for obj+cross (2 x 4M elems) ----------
__global__ __launch_bounds__(256) void cvt2_bf16(
    const float* __restrict__ a, const float* __restrict__ b,
    unsigned short* __restrict__ oa, unsigned short* __restrict__ ob)
{
  const int bid = blockIdx.x;
  const float* in = (bid < 4096) ? a : b;
  unsigned short* out = (bid < 4096) ? oa : ob;
  const int i = ((bid & 4095) * 256 + threadIdx.x) * 4;
  const float4 v = *(const float4*)(in + i);
  ushort4 o;
  o.x = f2bf(v.x); o.y = f2bf(v.y); o.z = f2bf(v.z); o.w = f2bf(v.w);
  *(ushort4*)(out + i) = o;
}

// ---------- fused weight cvts: Wq*0.125 -> Wall[0:1M), Wk -> Wall[1M:2M), Wo -> Wo_bf ----------
__global__ __launch_bounds__(256) void prep_w(
    const float* __restrict__ Wq, const float* __restrict__ Wk,
    const float* __restrict__ Wo,
    unsigned short* __restrict__ Wall, unsigned short* __restrict__ Wo_bf)
{
  const int bid = blockIdx.x;
  const int i = ((bid & 1023) * 256 + threadIdx.x) * 4;
  const float* in;
  unsigned short* out;
  float sc = 1.f;
  if (bid < 1024)      { in = Wq; out = Wall;           sc = 0.125f; }
  else if (bid < 2048) { in = Wk; out = Wall + 1048576; }
  else                 { in = Wo; out = Wo_bf; }
  const float4 v = *(const float4*)(in + i);
  ushort4 o;
  o.x = f2bf(v.x * sc); o.y = f2bf(v.y * sc);
  o.z = f2bf(v.z * sc); o.w = f2bf(v.w * sc);
  *(ushort4*)(out + i) = o;
}

// ---------- fp32 -> bf16 transposed (out[c][r] = in[r][c]) ----------
__global__ __launch_bounds__(256) void tcvt_bf16(
    const float* __restrict__ in, unsigned short* __restrict__ out, int R, int C)
{
  __shared__ float tile[32][33];
  const int bc = blockIdx.x * 32, br = blockIdx.y * 32;
  const int tx = threadIdx.x & 31, ty8 = threadIdx.x >> 5;
  #pragma unroll
  for (int j = 0; j < 32; j += 8)
    tile[ty8 + j][tx] = in[(size_t)(br + ty8 + j) * C + bc + tx];
  __syncthreads();
  #pragma unroll
  for (int j = 0; j < 32; j += 8)
    out[(size_t)(bc + ty8 + j) * R + br + tx] = f2bf(tile[tx][ty8 + j]);
}

// bov[g] = sum_f Wo[g][f] * bv[f]
__global__ __launch_bounds__(256) void bov_kernel(
    const float* __restrict__ Wo, const float* __restrict__ bv,
    float* __restrict__ bov)
{
  const int g    = blockIdx.x * 4 + (threadIdx.x >> 6);
  const int lane = threadIdx.x & 63;
  float acc = 0.f;
  for (int f = lane; f < 1024; f += 64)
    acc = fmaf(Wo[(size_t)g * 1024 + f], bv[f], acc);
  #pragma unroll
  for (int off = 32; off > 0; off >>= 1) acc += __shfl_down(acc, off);
  if (lane == 0) bov[g] = acc;
}

// ball[0:1024) = 0.125*bq ; ball[1024:2048) = bk
__global__ __launch_bounds__(256) void bias_prep(
    const float* __restrict__ bq, const float* __restrict__ bk,
    float* __restrict__ ball)
{
  const int i = blockIdx.x * 256 + threadIdx.x;
  ball[i]        = 0.125f * bq[i];
  ball[1024 + i] = bk[i];
}

// mb[i] = adj[i] > 0 ? lab[i] : NEG
__global__ __launch_bounds__(256) void mb_prep(
    const int* __restrict__ adj, const float* __restrict__ lab,
    float* __restrict__ mb)
{
  const int i = (blockIdx.x * 256 + threadIdx.x) * 4;
  const int4   a = *(const int4*)(adj + i);
  const float4 l = *(const float4*)(lab + i);
  float4 o;
  o.x = a.x > 0 ? l.x : NEGF;
  o.y = a.y > 0 ? l.y : NEGF;
  o.z = a.z > 0 ? l.z : NEGF;
  o.w = a.w > 0 ? l.w : NEGF;
  *(float4*)(mb + i) = o;
}

// ---------------------------------------------------------------
// Small reg-staged MFMA GEMM (Wov = Wo @ Wv, 1024^3).
// ---------------------------------------------------------------
__global__ __launch_bounds__(256) void gemm_wov(
    const unsigned short* __restrict__ A,
    const unsigned short* __restrict__ Bw,
    unsigned short* __restrict__ Cout,
    int M, int N, int K)
{
  __shared__ unsigned short Asm[128][72];
  __shared__ unsigned short Bsm[64][72];
  const int t = threadIdx.x;
  const int lane = t & 63, w = t >> 6;
  const int wm = w >> 1, wn = w & 1;
  const int bm = blockIdx.y * 128, bn = blockIdx.x * 64;

  f32x4 acc[4][2] = {};

  const int sr  = t >> 3;
  const int skq = (t & 7) * 8;
  const int fr  = lane & 15;
  const int kf  = (lane >> 4) * 8;

  for (int k0 = 0; k0 < K; k0 += 64) {
    const u16x8 a0 = *(const u16x8*)(A  + (size_t)(bm + sr)      * K + k0 + skq);
    const u16x8 a1 = *(const u16x8*)(A  + (size_t)(bm + sr + 32) * K + k0 + skq);
    const u16x8 a2 = *(const u16x8*)(A  + (size_t)(bm + sr + 64) * K + k0 + skq);
    const u16x8 a3 = *(const u16x8*)(A  + (size_t)(bm + sr + 96) * K + k0 + skq);
    const u16x8 b0 = *(const u16x8*)(Bw + (size_t)(bn + sr)      * K + k0 + skq);
    const u16x8 b1 = *(const u16x8*)(Bw + (size_t)(bn + sr + 32) * K + k0 + skq);
    __syncthreads();
    *(u16x8*)&Asm[sr][skq]      = a0;
    *(u16x8*)&Asm[sr + 32][skq] = a1;
    *(u16x8*)&Asm[sr + 64][skq] = a2;
    *(u16x8*)&Asm[sr + 96][skq] = a3;
    *(u16x8*)&Bsm[sr][skq]      = b0;
    *(u16x8*)&Bsm[sr + 32][skq] = b1;
    __syncthreads();

    s16x8 af[4][2], bf[2][2];
    #pragma unroll
    for (int fm = 0; fm < 4; ++fm)
      #pragma unroll
      for (int kk = 0; kk < 2; ++kk)
        af[fm][kk] = *(const s16x8*)&Asm[wm * 64 + fm * 16 + fr][kf + kk * 32];
    #pragma unroll
    for (int fn = 0; fn < 2; ++fn)
      #pragma unroll
      for (int kk = 0; kk < 2; ++kk)
        bf[fn][kk] = *(const s16x8*)&Bsm[wn * 32 + fn * 16 + fr][kf + kk * 32];

    #pragma unroll
    for (int fm = 0; fm < 4; ++fm)
      #pragma unroll
      for (int fn = 0; fn < 2; ++fn) {
        acc[fm][fn] = __builtin_amdgcn_mfma_f32_16x16x32_bf16(af[fm][0], bf[fn][0], acc[fm][fn], 0, 0, 0);
        acc[fm][fn] = __builtin_amdgcn_mfma_f32_16x16x32_bf16(af[fm][1], bf[fn][1], acc[fm][fn], 0, 0, 0);
      }
  }

  const int rg = (lane >> 4) * 4;
  #pragma unroll
  for (int fm = 0; fm < 4; ++fm)
    #pragma unroll
    for (int fn = 0; fn < 2; ++fn) {
      const int col = bn + wn * 32 + fn * 16 + fr;
      #pragma unroll
      for (int r = 0; r < 4; ++r) {
        const int row = bm + wm * 64 + fm * 16 + rg + r;
        Cout[(size_t)row * N + col] = f2bf(acc[fm][fn][r]);
      }
    }
}

// ---------------------------------------------------------------
// Fused projection GEMM (m97 structure) + bijective XCD 2D-chunk
// swizzle: xcd = bid&7 owns an 8bm x 12bn chunk (768 = 8 x 96),
// per-XCD L2 footprint ~5-7MB instead of whole-A x 8.
// ---------------------------------------------------------------
__global__ __launch_bounds__(256, 3) void gemm_big(
    const unsigned short* __restrict__ objA,
    const unsigned short* __restrict__ crossA,
    const unsigned short* __restrict__ Wall,   // [3072][1024]
    const float* __restrict__ ball,            // [3072]
    unsigned short* __restrict__ Qo,           // [4096][1024]
    unsigned short* __restrict__ Ko,           // [4096][1024]
    unsigned short* __restrict__ VWt)          // [B*1024][256]
{
  __shared__ unsigned short Asm[128 * 64];
  __shared__ unsigned short Bsm[128 * 64];
  const int t = threadIdx.x;
  const int w = t >> 6, lane = t & 63;
  const int wm = w >> 1, wn = w & 1;

  // XCD-aware decode: 8 chunks of (8 bm x 12 bn)
  const int bid = blockIdx.x;
  const int xcd = bid & 7, j = bid >> 3;            // j in [0,96)
  const int bmi = (xcd >> 1) * 8 + j / 12;          // [0,32)
  const int bni = (xcd & 1) * 12 + j % 12;          // [0,24)
  const int bm = bmi * 128;
  const int bn = bni * 128;
  const unsigned short* Ag = (bn < 1024) ? objA : crossA;

  const int srow = lane >> 3;
  const int skel = (lane & 7) * 8;
  const int fr = lane & 15, kf = (lane >> 4) * 8;

  f32x4 acc[4][4] = {};

  for (int k0 = 0; k0 < 1024; k0 += 64) {
    if (k0) __syncthreads();
    #pragma unroll
    for (int i = 0; i < 4; ++i) {
      const int c = i * 4 + w;
      const int r = c * 8 + srow;
      gload16(Ag   + (size_t)(bm + r) * 1024 + k0 + skel, &Asm[c * 512]);
      gload16(Wall + (size_t)(bn + r) * 1024 + k0 + skel, &Bsm[c * 512]);
    }
    __syncthreads();
    #pragma unroll
    for (int kk = 0; kk < 2; ++kk) {
      s16x8 af[4], bf[4];
      #pragma unroll
      for (int fm = 0; fm < 4; ++fm)
        af[fm] = *(const s16x8*)&Asm[(wm * 64 + fm * 16 + fr) * 64 + kk * 32 + kf];
      #pragma unroll
      for (int fn = 0; fn < 4; ++fn)
        bf[fn] = *(const s16x8*)&Bsm[(wn * 64 + fn * 16 + fr) * 64 + kk * 32 + kf];
      #pragma unroll
      for (int fm = 0; fm < 4; ++fm)
        #pragma unroll
        for (int fn = 0; fn < 4; ++fn)
          acc[fm][fn] = __builtin_amdgcn_mfma_f32_16x16x32_bf16(af[fm], bf[fn], acc[fm][fn], 0, 0, 0);
    }
  }

  const int rg = (lane >> 4) * 4;
  const int mode = bn >> 10;
  #pragma unroll
  for (int fm = 0; fm < 4; ++fm) {
    #pragma unroll
    for (int fn = 0; fn < 4; ++fn) {
      const int col  = bn + wn * 64 + fn * 16 + fr;
      const int cl   = col & 1023;
      const float bb = ball[col];
      const int row0 = bm + wm * 64 + fm * 16 + rg;
      if (mode == 0) {
        #pragma unroll
        for (int r = 0; r < 4; ++r)
          Qo[(size_t)(row0 + r) * 1024 + cl] = f2bf(acc[fm][fn][r] + bb);
      } else if (mode == 1) {
        #pragma unroll
        for (int r = 0; r < 4; ++r)
          Ko[(size_t)(row0 + r) * 1024 + cl] = f2bf(acc[fm][fn][r] + bb);
      } else {
        const int bidx = row0 >> 8, tok = row0 & 255;
        ushort4 u;
        u.x = f2bf(acc[fm][fn][0] + bb);
        u.y = f2bf(acc[fm][fn][1] + bb);
        u.z = f2bf(acc[fm][fn][2] + bb);
        u.w = f2bf(acc[fm][fn][3] + bb);
        *(ushort4*)(VWt + ((size_t)bidx * 1024 + cl) * 256 + tok) = u;
      }
    }
  }
}

// ---------------------------------------------------------------
// MFMA attention v4 (unchanged from r8).
// ---------------------------------------------------------------
__global__ __launch_bounds__(256, 2) void attn_mfma(
    const unsigned short* __restrict__ Qg,    // [B*256][1024] bf16, pre-scaled 1/8
    const unsigned short* __restrict__ Kg,    // [B*256][1024] bf16
    const unsigned short* __restrict__ VWt,   // [B*1024][256] bf16 ([b][h*64+d][k])
    const float* __restrict__ mb,             // [B][256][256] masked bias
    const float* __restrict__ bo,
    float* __restrict__ outp, unsigned short* __restrict__ Pb)
{
  const int t = threadIdx.x;
  const int w = t >> 6, lane = t & 63;
  const int fr = lane & 15, grp = lane >> 4;
  const int bid = blockIdx.x;
  const int qt = bid >> 8, hb = bid & 255;
  const int h = hb & 15, b = hb >> 4;
  const int q0 = qt * 64 + w * 16;

  __shared__ __align__(16) unsigned short Ks[256 * 64];    // 32 KB [k_row][d]
  __shared__ __align__(16) unsigned short VWs[64 * 256];   // 32 KB [d][k]

  // ---- DMA K slice (b,h): rows 128B, source col pre-swizzled ----
  {
    const unsigned short* kb = Kg + (size_t)(b * 256) * 1024 + h * 64;
    const int colb = (lane & 7) * 16;
    #pragma unroll
    for (int c = 0; c < 8; ++c) {
      const int row = c * 32 + w * 8 + (lane >> 3);
      const int sb  = colb ^ ((row & 7) << 4);
      gload16(kb + (size_t)row * 1024 + (sb >> 1), (char*)Ks + c * 4096 + w * 1024);
    }
  }
  // ---- DMA VW slice (b,h): rows 512B, source col pre-swizzled ----
  {
    const unsigned short* vwb = VWt + (size_t)(b * 16 + h) * 16384;
    const int xb = (lane & 31) * 16;
    #pragma unroll
    for (int c = 0; c < 8; ++c) {
      const int row = c * 8 + w * 2 + (lane >> 5);
      const int sb  = xb ^ ((row & 7) << 4);
      gload16(vwb + row * 256 + (sb >> 1), (char*)VWs + c * 4096 + w * 1024);
    }
  }

  // ---- Q B-frags (global, L2-hot) ----
  const unsigned short* qp = Qg + ((size_t)(b * 256 + q0 + fr)) * 1024 + h * 64 + grp * 8;
  const s16x8 qf0 = *(const s16x8*)qp;
  const s16x8 qf1 = *(const s16x8*)(qp + 32);

  __syncthreads();   // drains DMA (vmcnt 0) -> Ks/VWs ready

  // ---- S^T = K Q^T from LDS, mb from global, mask folded in ----
  const float* mbp = mb + ((size_t)(b * 256 + q0 + fr)) * 256 + grp * 4;
  const int colA = (grp * 16) ^ ((fr & 7) << 4);

  f32x4 s[16];
  #pragma unroll
  for (int nf = 0; nf < 16; ++nf) s[nf] = (f32x4){0.f, 0.f, 0.f, 0.f};

  s16x8 kA[8], kB[8];
  float4 mA[4], mB[4];
  float mx = -3e38f;

#define LOADB(KF, MF, nb)                                                    \
  { _Pragma("unroll") for (int i = 0; i < 4; ++i) {                          \
      const char* rp = (const char*)Ks + (((nb)*4 + i) * 16 + fr) * 128;     \
      KF[2*i]   = *(const s16x8*)(rp + colA);                                \
      KF[2*i+1] = *(const s16x8*)(rp + (colA ^ 64));                         \
      MF[i]     = *(const float4*)(mbp + ((nb)*4 + i) * 16); } }
#define MFMAB(KF, nb)                                                        \
  { _Pragma("unroll") for (int i = 0; i < 4; ++i) {                          \
      s[(nb)*4+i] = __builtin_amdgcn_mfma_f32_16x16x32_bf16(KF[2*i],   qf0, s[(nb)*4+i], 0, 0, 0); \
      s[(nb)*4+i] = __builtin_amdgcn_mfma_f32_16x16x32_bf16(KF[2*i+1], qf1, s[(nb)*4+i], 0, 0, 0); } }
#define MASKB(MF, nb)                                                        \
  { _Pragma("unroll") for (int i = 0; i < 4; ++i) {                          \
      _Pragma("unroll") for (int r = 0; r < 4; ++r) {                        \
        const float m = ((const float*)&MF[i])[r];                           \
        const float v = (m > -1e14f) ? s[(nb)*4+i][r] + m : m;               \
        s[(nb)*4+i][r] = v; mx = fmaxf(mx, v); } } }

  LOADB(kA, mA, 0); LOADB(kB, mB, 1); MFMAB(kA, 0);
  MASKB(mA, 0);     LOADB(kA, mA, 2); MFMAB(kB, 1);
  MASKB(mB, 1);     LOADB(kB, mB, 3); MFMAB(kA, 2);
  MASKB(mA, 2);     LOADB(kA, mA, 4); MFMAB(kB, 3);
  MASKB(mB, 3);     LOADB(kB, mB, 5); MFMAB(kA, 4);
  MASKB(mA, 4);     LOADB(kA, mA, 6); MFMAB(kB, 5);
  MASKB(mB, 5);     LOADB(kB, mB, 7); MFMAB(kA, 6);
  MASKB(mA, 6);     MFMAB(kB, 7);     MASKB(mB, 7);
#undef LOADB
#undef MFMAB
#undef MASKB

  // ---- softmax (row q = fr, spread over grp lanes) ----
  mx = fmaxf(mx, __shfl_xor(mx, 16));
  mx = fmaxf(mx, __shfl_xor(mx, 32));
  float sm = 0.f;
  #pragma unroll
  for (int nf = 0; nf < 16; ++nf)
    #pragma unroll
    for (int r = 0; r < 4; ++r) {
      const float e = __expf(s[nf][r] - mx);
      s[nf][r] = e;
      sm += e;
    }
  sm += __shfl_xor(sm, 16);
  sm += __shfl_xor(sm, 32);
  const float inv = 1.f / sm;

  // ---- pack P -> bf16 pairs in registers ----
  uint2 u2[16];
  #pragma unroll
  for (int nf = 0; nf < 16; ++nf) {
    const unsigned lo = (unsigned)f2bf(s[nf][0] * inv) | ((unsigned)f2bf(s[nf][1] * inv) << 16);
    const unsigned hi = (unsigned)f2bf(s[nf][2] * inv) | ((unsigned)f2bf(s[nf][3] * inv) << 16);
    u2[nf] = make_uint2(lo, hi);
  }

  // ---- Pb store (from regs; k = 16nf + 4grp + 0..3 for row q0+fr) ----
  unsigned short* prow = Pb + (((size_t)(b * 16 + h)) * 256 + q0 + fr) * 256 + grp * 4;
  #pragma unroll
  for (int nf = 0; nf < 16; ++nf)
    *(uint2*)(prow + nf * 16) = u2[nf];

  // ---- PV: pf via shuffles, vf via swizzled LDS reads ----
  f32x4 o[4];
  #pragma unroll
  for (int nf = 0; nf < 4; ++nf) o[nf] = (f32x4){0.f, 0.f, 0.f, 0.f};
  const int srcA = fr + ((grp & 1) << 5);
  const int srcB = srcA + 16;
  const int swz  = (fr & 7) << 4;
  const bool hiSel = (grp & 2);
  #pragma unroll
  for (int ks = 0; ks < 8; ++ks) {
    const int aLx = __shfl((int)u2[2 * ks].x,     srcA, 64);
    const int aLy = __shfl((int)u2[2 * ks].y,     srcA, 64);
    const int bLx = __shfl((int)u2[2 * ks].x,     srcB, 64);
    const int bLy = __shfl((int)u2[2 * ks].y,     srcB, 64);
    const int aHx = __shfl((int)u2[2 * ks + 1].x, srcA, 64);
    const int aHy = __shfl((int)u2[2 * ks + 1].y, srcA, 64);
    const int bHx = __shfl((int)u2[2 * ks + 1].x, srcB, 64);
    const int bHy = __shfl((int)u2[2 * ks + 1].y, srcB, 64);
    union { int4 i; s16x8 v; } pf;
    pf.i = hiSel ? make_int4(aHx, aHy, bHx, bHy) : make_int4(aLx, aLy, bLx, bLy);
    const int cb = (ks * 64 + grp * 16) ^ swz;
    #pragma unroll
    for (int nf = 0; nf < 4; ++nf) {
      const s16x8 vf = *(const s16x8*)((const char*)VWs + (nf * 16 + fr) * 512 + cb);
      o[nf] = __builtin_amdgcn_mfma_f32_16x16x32_bf16(pf.v, vf, o[nf], 0, 0, 0);
    }
  }

  // ---- epilogue: + bo, store f32 ----
  #pragma unroll
  for (int nf = 0; nf < 4; ++nf) {
    const float bb = bo[h * 64 + nf * 16 + fr];
    #pragma unroll
    for (int r = 0; r < 4; ++r)
      outp[((size_t)b * 256 + q0 + grp * 4 + r) * 1024 + h * 64 + nf * 16 + fr]
          = o[nf][r] + bb;
  }
}

// attm[b][q][k] = (1/16) sum_h Pb[b][h][q][k]
__global__ __launch_bounds__(256) void attm_reduce(
    const unsigned short* __restrict__ Pb, float* __restrict__ attm)
{
  const size_t idx = (size_t)blockIdx.x * 256 + threadIdx.x;
  const int    k8  = (int)(idx & 31);
  const size_t bq  = idx >> 5;
  const int    b   = (int)(bq >> 8);
  const int    q   = (int)(bq & 255);
  float s[8] = {};
  const unsigned short* base = Pb + (size_t)b * 1048576 + (size_t)q * 256 + k8 * 8;
  #pragma unroll
  for (int hh = 0; hh < 16; ++hh) {
    const u16x8 p = *(const u16x8*)(base + (size_t)hh * 65536);
    #pragma unroll
    for (int j = 0; j < 8; ++j) s[j] += bf2f(p[j]);
  }
  float* dst = attm + bq * 256 + k8 * 8;
  float4 r0, r1;
  r0.x = s[0] * 0.0625f; r0.y = s[1] * 0.0625f; r0.z = s[2] * 0.0625f; r0.w = s[3] * 0.0625f;
  r1.x = s[4] * 0.0625f; r1.y = s[5] * 0.0625f; r1.z = s[6] * 0.0625f; r1.w = s[7] * 0.0625f;
  *(float4*)dst = r0;
  *(float4*)(dst + 4) = r1;
}

// ---------------------------------------------------------------
extern "C" void kernel_launch(void* const* d_in, const int* in_sizes, int n_in,
                              void* d_out, int out_size, void* d_ws, size_t ws_size,
                              hipStream_t stream)
{
  const float* obj   = (const float*)d_in[0];
  const float* cross = (const float*)d_in[1];
  const int*   adj   = (const int*)d_in[2];
  const float* lab   = (const float*)d_in[3];
  const float* Wq    = (const float*)d_in[4];
  const float* bq    = (const float*)d_in[5];
  const float* Wk    = (const float*)d_in[6];
  const float* bk    = (const float*)d_in[7];
  const float* Wv    = (const float*)d_in[8];
  const float* bv    = (const float*)d_in[9];
  const float* Wo    = (const float*)d_in[10];
  const float* bo    = (const float*)d_in[11];

  float* out  = (float*)d_out;
  float* attm = out + (size_t)16 * 256 * 1024;

  // workspace layout (bytes)
  char* ws = (char*)d_ws;
  unsigned short* obj_bf   = (unsigned short*)(ws + 0);          // 8 MB (mbuf aliases later)
  unsigned short* cross_bf = (unsigned short*)(ws + 8388608);    // 8 MB
  unsigned short* Qbf      = (unsigned short*)(ws + 16777216);   // 8 MB
  unsigned short* Kbf      = (unsigned short*)(ws + 25165824);   // 8 MB
  unsigned short* VWt      = (unsigned short*)(ws + 33554432);   // 8 MB [B*1024][256]
  unsigned short* Wall     = (unsigned short*)(ws + 41943040);   // 6 MB [3072][1024]
  unsigned short* Wo_bf    = (unsigned short*)(ws + 48234496);   // 2 MB
  unsigned short* Wvt_bf   = (unsigned short*)(ws + 50331648);   // 2 MB (ball aliases after Wov gemm)
  float*          ball     = (float*)(ws + 50331648);            // 12 KB
  unsigned short* Pbuf     = (unsigned short*)(ws + 52432896);   // 32 MB
  float*          mbuf     = (float*)obj_bf;                     // 4 MB (after gemm_big)

  // fused fp32 -> bf16 conversions
  cvt2_bf16<<<8192, 256, 0, stream>>>(obj, cross, obj_bf, cross_bf);
  prep_w<<<3072, 256, 0, stream>>>(Wq, Wk, Wo, Wall, Wo_bf);
  tcvt_bf16<<<dim3(32, 32), 256, 0, stream>>>(Wv, Wvt_bf, 1024, 1024);

  // Wov = Wo @ Wv  -> Wall rows [2048, 3072)
  gemm_wov<<<dim3(16, 8), 256, 0, stream>>>(
      Wo_bf, Wvt_bf, Wall + 2097152, 1024, 1024, 1024);

  // bias vector [0.125*bq | bk | bov]  (ball aliases Wvt_bf: write after wov)
  bias_prep<<<4, 256, 0, stream>>>(bq, bk, ball);
  bov_kernel<<<256, 256, 0, stream>>>(Wo, bv, ball + 2048);

  // fused [Q | K | VW] projection (XCD-chunked 1D grid)
  gemm_big<<<768, 256, 0, stream>>>(
      obj_bf, cross_bf, Wall, ball, Qbf, Kbf, VWt);

  // obj_bf dead -> masked-bias table
  mb_prep<<<1024, 256, 0, stream>>>(adj, lab, mbuf);

  attn_mfma<<<1024, 256, 0, stream>>>(
      Qbf, Kbf, VWt, mbuf, bo, out, Pbuf);
  attm_reduce<<<512, 256, 0, stream>>>(Pbuf, attm);
}

// Round 10
// 119.657 us; speedup vs baseline: 1.6421x; 1.0342x over previous
//
#include <hip/hip_runtime.h>

#define NEGF -9e15f

typedef __attribute__((ext_vector_type(8))) unsigned short u16x8;
typedef __attribute__((ext_vector_type(8))) short          s16x8;
typedef __attribute__((ext_vector_type(4))) float          f32x4;

// ---------- bf16 helpers (RTN-even) ----------
__device__ __forceinline__ unsigned short f2bf(float x) {
  union { float f; unsigned int u; } c; c.f = x;
  unsigned int r = c.u + 0x7fffu + ((c.u >> 16) & 1u);
  return (unsigned short)(r >> 16);
}
__device__ __forceinline__ float bf2f(unsigned short v) {
  union { float f; unsigned int u; } c; c.u = ((unsigned int)v) << 16;
  return c.f;
}

// ---------- async global->LDS, 16B per lane (wave-uniform LDS base) ----------
__device__ __forceinline__ void gload16(const void* g, void* l) {
  __builtin_amdgcn_global_load_lds(
      (const __attribute__((address_space(1))) unsigned int*)g,
      (__attribute__((address_space(3))) unsigned int*)l, 16, 0, 0);
}

// ---------- fused fp32->bf16 for obj+cross (2 x 4M elems) ----------
__global__ __launch_bounds__(256) void cvt2_bf16(
    const float* __restrict__ a, const float* __restrict__ b,
    unsigned short* __restrict__ oa, unsigned short* __restrict__ ob)
{
  const int bid = blockIdx.x;
  const float* in = (bid < 4096) ? a : b;
  unsigned short* out = (bid < 4096) ? oa : ob;
  const int i = ((bid & 4095) * 256 + threadIdx.x) * 4;
  const float4 v = *(const float4*)(in + i);
  ushort4 o;
  o.x = f2bf(v.x); o.y = f2bf(v.y); o.z = f2bf(v.z); o.w = f2bf(v.w);
  *(ushort4*)(out + i) = o;
}

// ---------- fused weight prep: Wq*0.125, Wk, Wo (elementwise) + Wv transpose ----------
__global__ __launch_bounds__(256) void prep_w(
    const float* __restrict__ Wq, const float* __restrict__ Wk,
    const float* __restrict__ Wo, const float* __restrict__ Wv,
    unsigned short* __restrict__ Wall, unsigned short* __restrict__ Wo_bf,
    unsigned short* __restrict__ Wvt_bf)
{
  __shared__ float tile[32][33];
  const int bid = blockIdx.x;
  if (bid < 3072) {
    const int i = ((bid & 1023) * 256 + threadIdx.x) * 4;
    const float* in;
    unsigned short* out;
    float sc = 1.f;
    if (bid < 1024)      { in = Wq; out = Wall;           sc = 0.125f; }
    else if (bid < 2048) { in = Wk; out = Wall + 1048576; }
    else                 { in = Wo; out = Wo_bf; }
    const float4 v = *(const float4*)(in + i);
    ushort4 o;
    o.x = f2bf(v.x * sc); o.y = f2bf(v.y * sc);
    o.z = f2bf(v.z * sc); o.w = f2bf(v.w * sc);
    *(ushort4*)(out + i) = o;
  } else {
    // transpose-convert Wv -> Wvt_bf (1024x1024)
    const int j = bid - 3072;
    const int bc = (j & 31) * 32, br = (j >> 5) * 32;
    const int tx = threadIdx.x & 31, ty8 = threadIdx.x >> 5;
    #pragma unroll
    for (int jj = 0; jj < 32; jj += 8)
      tile[ty8 + jj][tx] = Wv[(size_t)(br + ty8 + jj) * 1024 + bc + tx];
    __syncthreads();
    #pragma unroll
    for (int jj = 0; jj < 32; jj += 8)
      Wvt_bf[(size_t)(bc + ty8 + jj) * 1024 + br + tx] = f2bf(tile[tx][ty8 + jj]);
  }
}

// ---------- fused bias prep: ball = [0.125*bq | bk | Wo@bv] ----------
__global__ __launch_bounds__(256) void prep_bias(
    const float* __restrict__ bq, const float* __restrict__ bk,
    const float* __restrict__ Wo, const float* __restrict__ bv,
    float* __restrict__ ball)
{
  const int bid = blockIdx.x;
  if (bid < 4) {
    const int i = bid * 256 + threadIdx.x;
    ball[i]        = 0.125f * bq[i];
    ball[1024 + i] = bk[i];
  } else {
    const int g    = (bid - 4) * 4 + (threadIdx.x >> 6);
    const int lane = threadIdx.x & 63;
    float acc = 0.f;
    for (int f = lane; f < 1024; f += 64)
      acc = fmaf(Wo[(size_t)g * 1024 + f], bv[f], acc);
    #pragma unroll
    for (int off = 32; off > 0; off >>= 1) acc += __shfl_down(acc, off);
    if (lane == 0) ball[2048 + g] = acc;
  }
}

// mb[i] = adj[i] > 0 ? lab[i] : NEG
__global__ __launch_bounds__(256) void mb_prep(
    const int* __restrict__ adj, const float* __restrict__ lab,
    float* __restrict__ mb)
{
  const int i = (blockIdx.x * 256 + threadIdx.x) * 4;
  const int4   a = *(const int4*)(adj + i);
  const float4 l = *(const float4*)(lab + i);
  float4 o;
  o.x = a.x > 0 ? l.x : NEGF;
  o.y = a.y > 0 ? l.y : NEGF;
  o.z = a.z > 0 ? l.z : NEGF;
  o.w = a.w > 0 ? l.w : NEGF;
  *(float4*)(mb + i) = o;
}

// ---------------------------------------------------------------
// Wov = Wo @ Wv (1024^3), m97-style global_load_lds staging.
// BM=128 BN=64 BK=64, grid (16,8), 256 threads = 4 waves.
// ---------------------------------------------------------------
__global__ __launch_bounds__(256, 3) void gemm_wov(
    const unsigned short* __restrict__ A,
    const unsigned short* __restrict__ Bw,
    unsigned short* __restrict__ Cout)
{
  __shared__ unsigned short Asm[128 * 64];
  __shared__ unsigned short Bsm[64 * 64];
  const int t = threadIdx.x;
  const int lane = t & 63, w = t >> 6;
  const int wm = w >> 1, wn = w & 1;
  const int bm = blockIdx.y * 128, bn = blockIdx.x * 64;

  const int srow = lane >> 3;          // 0..7
  const int skel = (lane & 7) * 8;     // elems
  const int fr = lane & 15, kf = (lane >> 4) * 8;

  f32x4 acc[4][2] = {};

  for (int k0 = 0; k0 < 1024; k0 += 64) {
    if (k0) __syncthreads();
    #pragma unroll
    for (int i = 0; i < 4; ++i) {
      const int c = i * 4 + w;         // A chunks 0..15 (8 rows each)
      const int r = c * 8 + srow;
      gload16(A + (size_t)(bm + r) * 1024 + k0 + skel, &Asm[c * 512]);
    }
    #pragma unroll
    for (int i = 0; i < 2; ++i) {
      const int c = i * 4 + w;         // B chunks 0..7
      const int r = c * 8 + srow;
      gload16(Bw + (size_t)(bn + r) * 1024 + k0 + skel, &Bsm[c * 512]);
    }
    __syncthreads();
    #pragma unroll
    for (int kk = 0; kk < 2; ++kk) {
      s16x8 af[4], bf[2];
      #pragma unroll
      for (int fm = 0; fm < 4; ++fm)
        af[fm] = *(const s16x8*)&Asm[(wm * 64 + fm * 16 + fr) * 64 + kk * 32 + kf];
      #pragma unroll
      for (int fn = 0; fn < 2; ++fn)
        bf[fn] = *(const s16x8*)&Bsm[(wn * 32 + fn * 16 + fr) * 64 + kk * 32 + kf];
      #pragma unroll
      for (int fm = 0; fm < 4; ++fm)
        #pragma unroll
        for (int fn = 0; fn < 2; ++fn)
          acc[fm][fn] = __builtin_amdgcn_mfma_f32_16x16x32_bf16(af[fm], bf[fn], acc[fm][fn], 0, 0, 0);
    }
  }

  const int rg = (lane >> 4) * 4;
  #pragma unroll
  for (int fm = 0; fm < 4; ++fm)
    #pragma unroll
    for (int fn = 0; fn < 2; ++fn) {
      const int col = bn + wn * 32 + fn * 16 + fr;
      #pragma unroll
      for (int r = 0; r < 4; ++r) {
        const int row = bm + wm * 64 + fm * 16 + rg + r;
        Cout[(size_t)row * 1024 + col] = f2bf(acc[fm][fn][r]);
      }
    }
}

// ---------------------------------------------------------------
// Fused projection GEMM (m97 structure) + bijective XCD 2D-chunk
// swizzle (unchanged from r9).
// ---------------------------------------------------------------
__global__ __launch_bounds__(256, 3) void gemm_big(
    const unsigned short* __restrict__ objA,
    const unsigned short* __restrict__ crossA,
    const unsigned short* __restrict__ Wall,   // [3072][1024]
    const float* __restrict__ ball,            // [3072]
    unsigned short* __restrict__ Qo,           // [4096][1024]
    unsigned short* __restrict__ Ko,           // [4096][1024]
    unsigned short* __restrict__ VWt)          // [B*1024][256]
{
  __shared__ unsigned short Asm[128 * 64];
  __shared__ unsigned short Bsm[128 * 64];
  const int t = threadIdx.x;
  const int w = t >> 6, lane = t & 63;
  const int wm = w >> 1, wn = w & 1;

  const int bid = blockIdx.x;
  const int xcd = bid & 7, j = bid >> 3;
  const int bmi = (xcd >> 1) * 8 + j / 12;
  const int bni = (xcd & 1) * 12 + j % 12;
  const int bm = bmi * 128;
  const int bn = bni * 128;
  const unsigned short* Ag = (bn < 1024) ? objA : crossA;

  const int srow = lane >> 3;
  const int skel = (lane & 7) * 8;
  const int fr = lane & 15, kf = (lane >> 4) * 8;

  f32x4 acc[4][4] = {};

  for (int k0 = 0; k0 < 1024; k0 += 64) {
    if (k0) __syncthreads();
    #pragma unroll
    for (int i = 0; i < 4; ++i) {
      const int c = i * 4 + w;
      const int r = c * 8 + srow;
      gload16(Ag   + (size_t)(bm + r) * 1024 + k0 + skel, &Asm[c * 512]);
      gload16(Wall + (size_t)(bn + r) * 1024 + k0 + skel, &Bsm[c * 512]);
    }
    __syncthreads();
    #pragma unroll
    for (int kk = 0; kk < 2; ++kk) {
      s16x8 af[4], bf[4];
      #pragma unroll
      for (int fm = 0; fm < 4; ++fm)
        af[fm] = *(const s16x8*)&Asm[(wm * 64 + fm * 16 + fr) * 64 + kk * 32 + kf];
      #pragma unroll
      for (int fn = 0; fn < 4; ++fn)
        bf[fn] = *(const s16x8*)&Bsm[(wn * 64 + fn * 16 + fr) * 64 + kk * 32 + kf];
      #pragma unroll
      for (int fm = 0; fm < 4; ++fm)
        #pragma unroll
        for (int fn = 0; fn < 4; ++fn)
          acc[fm][fn] = __builtin_amdgcn_mfma_f32_16x16x32_bf16(af[fm], bf[fn], acc[fm][fn], 0, 0, 0);
    }
  }

  const int rg = (lane >> 4) * 4;
  const int mode = bn >> 10;
  #pragma unroll
  for (int fm = 0; fm < 4; ++fm) {
    #pragma unroll
    for (int fn = 0; fn < 4; ++fn) {
      const int col  = bn + wn * 64 + fn * 16 + fr;
      const int cl   = col & 1023;
      const float bb = ball[col];
      const int row0 = bm + wm * 64 + fm * 16 + rg;
      if (mode == 0) {
        #pragma unroll
        for (int r = 0; r < 4; ++r)
          Qo[(size_t)(row0 + r) * 1024 + cl] = f2bf(acc[fm][fn][r] + bb);
      } else if (mode == 1) {
        #pragma unroll
        for (int r = 0; r < 4; ++r)
          Ko[(size_t)(row0 + r) * 1024 + cl] = f2bf(acc[fm][fn][r] + bb);
      } else {
        const int bidx = row0 >> 8, tok = row0 & 255;
        ushort4 u;
        u.x = f2bf(acc[fm][fn][0] + bb);
        u.y = f2bf(acc[fm][fn][1] + bb);
        u.z = f2bf(acc[fm][fn][2] + bb);
        u.w = f2bf(acc[fm][fn][3] + bb);
        *(ushort4*)(VWt + ((size_t)bidx * 1024 + cl) * 256 + tok) = u;
      }
    }
  }
}

// ---------------------------------------------------------------
// MFMA attention v5 = v4 + XCD-clustered bid decode: xcd owns 2 b's
// (all qt, h) -> per-XCD L2 set ~3.5MB (mb 0.5 + K 1 + VW 1 + Q 1).
// ---------------------------------------------------------------
__global__ __launch_bounds__(256, 2) void attn_mfma(
    const unsigned short* __restrict__ Qg,    // [B*256][1024] bf16, pre-scaled 1/8
    const unsigned short* __restrict__ Kg,    // [B*256][1024] bf16
    const unsigned short* __restrict__ VWt,   // [B*1024][256] bf16 ([b][h*64+d][k])
    const float* __restrict__ mb,             // [B][256][256] masked bias
    const float* __restrict__ bo,
    float* __restrict__ outp, unsigned short* __restrict__ Pb)
{
  const int t = threadIdx.x;
  const int w = t >> 6, lane = t & 63;
  const int fr = lane & 15, grp = lane >> 4;
  // XCD-clustered decode: xcd = bid&7 gets bqt in [xcd*8, xcd*8+8)
  const int bid = blockIdx.x;
  const int xcd = bid & 7, i = bid >> 3;     // i in [0,128)
  const int h   = i & 15;
  const int bqt = xcd * 8 + (i >> 4);        // [0,64)
  const int b   = bqt >> 2;
  const int qt  = bqt & 3;
  const int q0 = qt * 64 + w * 16;

  __shared__ __align__(16) unsigned short Ks[256 * 64];    // 32 KB [k_row][d]
  __shared__ __align__(16) unsigned short VWs[64 * 256];   // 32 KB [d][k]

  // ---- DMA K slice (b,h): rows 128B, source col pre-swizzled ----
  {
    const unsigned short* kb = Kg + (size_t)(b * 256) * 1024 + h * 64;
    const int colb = (lane & 7) * 16;
    #pragma unroll
    for (int c = 0; c < 8; ++c) {
      const int row = c * 32 + w * 8 + (lane >> 3);
      const int sb  = colb ^ ((row & 7) << 4);
      gload16(kb + (size_t)row * 1024 + (sb >> 1), (char*)Ks + c * 4096 + w * 1024);
    }
  }
  // ---- DMA VW slice (b,h): rows 512B, source col pre-swizzled ----
  {
    const unsigned short* vwb = VWt + (size_t)(b * 16 + h) * 16384;
    const int xb = (lane & 31) * 16;
    #pragma unroll
    for (int c = 0; c < 8; ++c) {
      const int row = c * 8 + w * 2 + (lane >> 5);
      const int sb  = xb ^ ((row & 7) << 4);
      gload16(vwb + row * 256 + (sb >> 1), (char*)VWs + c * 4096 + w * 1024);
    }
  }

  // ---- Q B-frags (global, L2-hot) ----
  const unsigned short* qp = Qg + ((size_t)(b * 256 + q0 + fr)) * 1024 + h * 64 + grp * 8;
  const s16x8 qf0 = *(const s16x8*)qp;
  const s16x8 qf1 = *(const s16x8*)(qp + 32);

  __syncthreads();   // drains DMA (vmcnt 0) -> Ks/VWs ready

  // ---- S^T = K Q^T from LDS, mb from global, mask folded in ----
  const float* mbp = mb + ((size_t)(b * 256 + q0 + fr)) * 256 + grp * 4;
  const int colA = (grp * 16) ^ ((fr & 7) << 4);

  f32x4 s[16];
  #pragma unroll
  for (int nf = 0; nf < 16; ++nf) s[nf] = (f32x4){0.f, 0.f, 0.f, 0.f};

  s16x8 kA[8], kB[8];
  float4 mA[4], mB[4];
  float mx = -3e38f;

#define LOADB(KF, MF, nb)                                                    \
  { _Pragma("unroll") for (int i2 = 0; i2 < 4; ++i2) {                       \
      const char* rp = (const char*)Ks + (((nb)*4 + i2) * 16 + fr) * 128;    \
      KF[2*i2]   = *(const s16x8*)(rp + colA);                               \
      KF[2*i2+1] = *(const s16x8*)(rp + (colA ^ 64));                        \
      MF[i2]     = *(const float4*)(mbp + ((nb)*4 + i2) * 16); } }
#define MFMAB(KF, nb)                                                        \
  { _Pragma("unroll") for (int i2 = 0; i2 < 4; ++i2) {                       \
      s[(nb)*4+i2] = __builtin_amdgcn_mfma_f32_16x16x32_bf16(KF[2*i2],   qf0, s[(nb)*4+i2], 0, 0, 0); \
      s[(nb)*4+i2] = __builtin_amdgcn_mfma_f32_16x16x32_bf16(KF[2*i2+1], qf1, s[(nb)*4+i2], 0, 0, 0); } }
#define MASKB(MF, nb)                                                        \
  { _Pragma("unroll") for (int i2 = 0; i2 < 4; ++i2) {                       \
      _Pragma("unroll") for (int r = 0; r < 4; ++r) {                        \
        const float m = ((const float*)&MF[i2])[r];                          \
        const float v = (m > -1e14f) ? s[(nb)*4+i2][r] + m : m;              \
        s[(nb)*4+i2][r] = v; mx = fmaxf(mx, v); } } }

  LOADB(kA, mA, 0); LOADB(kB, mB, 1); MFMAB(kA, 0);
  MASKB(mA, 0);     LOADB(kA, mA, 2); MFMAB(kB, 1);
  MASKB(mB, 1);     LOADB(kB, mB, 3); MFMAB(kA, 2);
  MASKB(mA, 2);     LOADB(kA, mA, 4); MFMAB(kB, 3);
  MASKB(mB, 3);     LOADB(kB, mB, 5); MFMAB(kA, 4);
  MASKB(mA, 4);     LOADB(kA, mA, 6); MFMAB(kB, 5);
  MASKB(mB, 5);     LOADB(kB, mB, 7); MFMAB(kA, 6);
  MASKB(mA, 6);     MFMAB(kB, 7);     MASKB(mB, 7);
#undef LOADB
#undef MFMAB
#undef MASKB

  // ---- softmax (row q = fr, spread over grp lanes) ----
  mx = fmaxf(mx, __shfl_xor(mx, 16));
  mx = fmaxf(mx, __shfl_xor(mx, 32));
  float sm = 0.f;
  #pragma unroll
  for (int nf = 0; nf < 16; ++nf)
    #pragma unroll
    for (int r = 0; r < 4; ++r) {
      const float e = __expf(s[nf][r] - mx);
      s[nf][r] = e;
      sm += e;
    }
  sm += __shfl_xor(sm, 16);
  sm += __shfl_xor(sm, 32);
  const float inv = 1.f / sm;

  // ---- pack P -> bf16 pairs in registers ----
  uint2 u2[16];
  #pragma unroll
  for (int nf = 0; nf < 16; ++nf) {
    const unsigned lo = (unsigned)f2bf(s[nf][0] * inv) | ((unsigned)f2bf(s[nf][1] * inv) << 16);
    const unsigned hi = (unsigned)f2bf(s[nf][2] * inv) | ((unsigned)f2bf(s[nf][3] * inv) << 16);
    u2[nf] = make_uint2(lo, hi);
  }

  // ---- Pb store (from regs; k = 16nf + 4grp + 0..3 for row q0+fr) ----
  unsigned short* prow = Pb + (((size_t)(b * 16 + h)) * 256 + q0 + fr) * 256 + grp * 4;
  #pragma unroll
  for (int nf = 0; nf < 16; ++nf)
    *(uint2*)(prow + nf * 16) = u2[nf];

  // ---- PV: pf via shuffles, vf via swizzled LDS reads ----
  f32x4 o[4];
  #pragma unroll
  for (int nf = 0; nf < 4; ++nf) o[nf] = (f32x4){0.f, 0.f, 0.f, 0.f};
  const int srcA = fr + ((grp & 1) << 5);
  const int srcB = srcA + 16;
  const int swz  = (fr & 7) << 4;
  const bool hiSel = (grp & 2);
  #pragma unroll
  for (int ks = 0; ks < 8; ++ks) {
    const int aLx = __shfl((int)u2[2 * ks].x,     srcA, 64);
    const int aLy = __shfl((int)u2[2 * ks].y,     srcA, 64);
    const int bLx = __shfl((int)u2[2 * ks].x,     srcB, 64);
    const int bLy = __shfl((int)u2[2 * ks].y,     srcB, 64);
    const int aHx = __shfl((int)u2[2 * ks + 1].x, srcA, 64);
    const int aHy = __shfl((int)u2[2 * ks + 1].y, srcA, 64);
    const int bHx = __shfl((int)u2[2 * ks + 1].x, srcB, 64);
    const int bHy = __shfl((int)u2[2 * ks + 1].y, srcB, 64);
    union { int4 i; s16x8 v; } pf;
    pf.i = hiSel ? make_int4(aHx, aHy, bHx, bHy) : make_int4(aLx, aLy, bLx, bLy);
    const int cb = (ks * 64 + grp * 16) ^ swz;
    #pragma unroll
    for (int nf = 0; nf < 4; ++nf) {
      const s16x8 vf = *(const s16x8*)((const char*)VWs + (nf * 16 + fr) * 512 + cb);
      o[nf] = __builtin_amdgcn_mfma_f32_16x16x32_bf16(pf.v, vf, o[nf], 0, 0, 0);
    }
  }

  // ---- epilogue: + bo, store f32 ----
  #pragma unroll
  for (int nf = 0; nf < 4; ++nf) {
    const float bb = bo[h * 64 + nf * 16 + fr];
    #pragma unroll
    for (int r = 0; r < 4; ++r)
      outp[((size_t)b * 256 + q0 + grp * 4 + r) * 1024 + h * 64 + nf * 16 + fr]
          = o[nf][r] + bb;
  }
}

// attm[b][q][k] = (1/16) sum_h Pb[b][h][q][k]
__global__ __launch_bounds__(256) void attm_reduce(
    const unsigned short* __restrict__ Pb, float* __restrict__ attm)
{
  const size_t idx = (size_t)blockIdx.x * 256 + threadIdx.x;
  const int    k8  = (int)(idx & 31);
  const size_t bq  = idx >> 5;
  const int    b   = (int)(bq >> 8);
  const int    q   = (int)(bq & 255);
  float s[8] = {};
  const unsigned short* base = Pb + (size_t)b * 1048576 + (size_t)q * 256 + k8 * 8;
  #pragma unroll
  for (int hh = 0; hh < 16; ++hh) {
    const u16x8 p = *(const u16x8*)(base + (size_t)hh * 65536);
    #pragma unroll
    for (int j = 0; j < 8; ++j) s[j] += bf2f(p[j]);
  }
  float* dst = attm + bq * 256 + k8 * 8;
  float4 r0, r1;
  r0.x = s[0] * 0.0625f; r0.y = s[1] * 0.0625f; r0.z = s[2] * 0.0625f; r0.w = s[3] * 0.0625f;
  r1.x = s[4] * 0.0625f; r1.y = s[5] * 0.0625f; r1.z = s[6] * 0.0625f; r1.w = s[7] * 0.0625f;
  *(float4*)dst = r0;
  *(float4*)(dst + 4) = r1;
}

// ---------------------------------------------------------------
extern "C" void kernel_launch(void* const* d_in, const int* in_sizes, int n_in,
                              void* d_out, int out_size, void* d_ws, size_t ws_size,
                              hipStream_t stream)
{
  const float* obj   = (const float*)d_in[0];
  const float* cross = (const float*)d_in[1];
  const int*   adj   = (const int*)d_in[2];
  const float* lab   = (const float*)d_in[3];
  const float* Wq    = (const float*)d_in[4];
  const float* bq    = (const float*)d_in[5];
  const float* Wk    = (const float*)d_in[6];
  const float* bk    = (const float*)d_in[7];
  const float* Wv    = (const float*)d_in[8];
  const float* bv    = (const float*)d_in[9];
  const float* Wo    = (const float*)d_in[10];
  const float* bo    = (const float*)d_in[11];

  float* out  = (float*)d_out;
  float* attm = out + (size_t)16 * 256 * 1024;

  // workspace layout (bytes)
  char* ws = (char*)d_ws;
  unsigned short* obj_bf   = (unsigned short*)(ws + 0);          // 8 MB (mbuf aliases later)
  unsigned short* cross_bf = (unsigned short*)(ws + 8388608);    // 8 MB
  unsigned short* Qbf      = (unsigned short*)(ws + 16777216);   // 8 MB
  unsigned short* Kbf      = (unsigned short*)(ws + 25165824);   // 8 MB
  unsigned short* VWt      = (unsigned short*)(ws + 33554432);   // 8 MB [B*1024][256]
  unsigned short* Wall     = (unsigned short*)(ws + 41943040);   // 6 MB [3072][1024]
  unsigned short* Wo_bf    = (unsigned short*)(ws + 48234496);   // 2 MB
  unsigned short* Wvt_bf   = (unsigned short*)(ws + 50331648);   // 2 MB (ball aliases after Wov gemm)
  float*          ball     = (float*)(ws + 50331648);            // 12 KB
  unsigned short* Pbuf     = (unsigned short*)(ws + 52432896);   // 32 MB
  float*          mbuf     = (float*)obj_bf;                     // 4 MB (after gemm_big)

  // fused fp32 -> bf16 conversions (8 kernels total in the whole pipeline)
  cvt2_bf16<<<8192, 256, 0, stream>>>(obj, cross, obj_bf, cross_bf);
  prep_w<<<4096, 256, 0, stream>>>(Wq, Wk, Wo, Wv, Wall, Wo_bf, Wvt_bf);

  // Wov = Wo @ Wv  -> Wall rows [2048, 3072)
  gemm_wov<<<dim3(16, 8), 256, 0, stream>>>(Wo_bf, Wvt_bf, Wall + 2097152);

  // bias vector [0.125*bq | bk | bov]  (ball aliases Wvt_bf: write after wov)
  prep_bias<<<260, 256, 0, stream>>>(bq, bk, Wo, bv, ball);

  // fused [Q | K | VW] projection (XCD-chunked 1D grid)
  gemm_big<<<768, 256, 0, stream>>>(
      obj_bf, cross_bf, Wall, ball, Qbf, Kbf, VWt);

  // obj_bf dead -> masked-bias table
  mb_prep<<<1024, 256, 0, stream>>>(adj, lab, mbuf);

  attn_mfma<<<1024, 256, 0, stream>>>(
      Qbf, Kbf, VWt, mbuf, bo, out, Pbuf);
  attm_reduce<<<512, 256, 0, stream>>>(Pbuf, attm);
}